// Round 1
// baseline (1021.801 us; speedup 1.0000x reference)
//
#include <hip/hip_runtime.h>

// GraphSAGE 4-layer encoder, N=100000 nodes, d=64, E=1.6M edges.
// Strategy:
//   1. Build CSR (by dst) once per launch: detect int32/int64 edge_index,
//      count degrees, prefix-scan, fill adjacency (int atomics only).
//   2. Per layer: GEMM pass P = h@Wl, R = h@Wr + bl  (linearity of mean:
//      mean(h[src])@Wl == mean(P[src])), then fused gather kernel:
//      h_out = act(invdeg * sum P[nbr] + R) [+residual] [L2-normalize].

static inline size_t al256(size_t x) { return (x + 255) & ~(size_t)255; }

// ---- edge dtype detection: int64 little-endian values < 2^31 have all odd
// 32-bit words zero. flag=1 -> int32, flag=0 -> int64.
__global__ void k_detect(const unsigned int* __restrict__ raw, int E, int* __restrict__ flag) {
  int i = blockIdx.x * 256 + threadIdx.x;
  bool nz = (i < E) && (raw[2 * i + 1] != 0u);
  unsigned long long b = __ballot(nz);
  if ((threadIdx.x & 63) == 0 && b) atomicOr(flag, 1);
}

__global__ void k_count(const unsigned int* __restrict__ raw, int E,
                        const int* __restrict__ flag, int* __restrict__ deg) {
  int i = blockIdx.x * 256 + threadIdx.x;
  if (i >= E) return;
  int f = *flag;
  int dst = f ? (int)raw[E + i] : (int)raw[2 * (E + i)];
  atomicAdd(&deg[dst], 1);
}

__global__ void k_scan1(const int* __restrict__ deg, int* __restrict__ bsum, int n) {
  int i = blockIdx.x * 256 + threadIdx.x;
  int v = (i < n) ? deg[i] : 0;
#pragma unroll
  for (int m = 1; m < 64; m <<= 1) v += __shfl_xor(v, m, 64);
  __shared__ int ls[4];
  if ((threadIdx.x & 63) == 0) ls[threadIdx.x >> 6] = v;
  __syncthreads();
  if (threadIdx.x == 0) bsum[blockIdx.x] = ls[0] + ls[1] + ls[2] + ls[3];
}

__global__ void k_scan2(int* __restrict__ bsum, int nch) {
  __shared__ int s[512];
  int t = threadIdx.x;
  int v = (t < nch) ? bsum[t] : 0;
  s[t] = v;
  __syncthreads();
  for (int off = 1; off < 512; off <<= 1) {
    int add = (t >= off) ? s[t - off] : 0;
    __syncthreads();
    s[t] += add;
    __syncthreads();
  }
  if (t < nch) bsum[t] = s[t] - v;  // exclusive
}

__global__ void k_scan3(const int* __restrict__ deg, const int* __restrict__ bsum,
                        int* __restrict__ rs, int* __restrict__ cursor,
                        float* __restrict__ invdeg, int n) {
  __shared__ int s[256];
  int t = threadIdx.x;
  int i = blockIdx.x * 256 + t;
  int d = (i < n) ? deg[i] : 0;
  s[t] = d;
  __syncthreads();
  for (int off = 1; off < 256; off <<= 1) {
    int add = (t >= off) ? s[t - off] : 0;
    __syncthreads();
    s[t] += add;
    __syncthreads();
  }
  int ex = s[t] - d + bsum[blockIdx.x];
  if (i < n) {
    rs[i] = ex;
    cursor[i] = ex;
    invdeg[i] = 1.0f / fmaxf((float)d, 1.0f);
    if (i == n - 1) rs[n] = ex + d;
  }
}

__global__ void k_fill(const unsigned int* __restrict__ raw, int E,
                       const int* __restrict__ flag, int* __restrict__ cursor,
                       int* __restrict__ csr) {
  int i = blockIdx.x * 256 + threadIdx.x;
  if (i >= E) return;
  int f = *flag;
  int src = f ? (int)raw[i] : (int)raw[2 * i];
  int dst = f ? (int)raw[E + i] : (int)raw[2 * (E + i)];
  int pos = atomicAdd(&cursor[dst], 1);
  csr[pos] = src;
}

// ---- GEMM: P = h @ Wl ; R = h @ Wr + bl.  Block tile: 64 nodes x 128 cols.
// 256 threads, each computes 4 rows x 8 cols of the concatenated [Wl|Wr].
__global__ __launch_bounds__(256) void k_gemm(
    const float* __restrict__ h, const float* __restrict__ Wl,
    const float* __restrict__ Wr, const float* __restrict__ bl,
    float* __restrict__ P, float* __restrict__ R, int n) {
  __shared__ float hT[64][68];   // transposed h tile, padded: 16B-aligned float4 rows
  __shared__ float W2[64][128];  // [k][j]: j<64 -> Wl, else Wr
  int t = threadIdx.x;
  int n0 = blockIdx.x * 64;

  for (int idx = t; idx < 64 * 128; idx += 256) {
    int k = idx >> 7, j = idx & 127;
    W2[k][j] = (j < 64) ? Wl[k * 64 + j] : Wr[k * 64 + (j - 64)];
  }
  for (int idx = t; idx < 64 * 16; idx += 256) {
    int r = idx >> 4;
    int k4 = (idx & 15) * 4;
    int nn = n0 + r;
    float4 hv = (nn < n) ? *(const float4*)&h[(size_t)nn * 64 + k4]
                         : make_float4(0.f, 0.f, 0.f, 0.f);
    hT[k4 + 0][r] = hv.x;
    hT[k4 + 1][r] = hv.y;
    hT[k4 + 2][r] = hv.z;
    hT[k4 + 3][r] = hv.w;
  }
  __syncthreads();

  int j0 = (t & 15) * 8;
  int r0 = (t >> 4) * 4;
  float acc[4][8] = {};
#pragma unroll 8
  for (int k = 0; k < 64; ++k) {
    float4 hv = *(const float4*)&hT[k][r0];
    float wv[8];
    *(float4*)&wv[0] = *(const float4*)&W2[k][j0];
    *(float4*)&wv[4] = *(const float4*)&W2[k][j0 + 4];
    float hr[4] = {hv.x, hv.y, hv.z, hv.w};
#pragma unroll
    for (int r = 0; r < 4; ++r)
#pragma unroll
      for (int c = 0; c < 8; ++c) acc[r][c] = fmaf(hr[r], wv[c], acc[r][c]);
  }

  if (j0 < 64) {
#pragma unroll
    for (int r = 0; r < 4; ++r) {
      int nn = n0 + r0 + r;
      if (nn < n) {
        *(float4*)&P[(size_t)nn * 64 + j0] = make_float4(acc[r][0], acc[r][1], acc[r][2], acc[r][3]);
        *(float4*)&P[(size_t)nn * 64 + j0 + 4] = make_float4(acc[r][4], acc[r][5], acc[r][6], acc[r][7]);
      }
    }
  } else {
    int jj = j0 - 64;
    float4 b0 = *(const float4*)&bl[jj];
    float4 b1 = *(const float4*)&bl[jj + 4];
#pragma unroll
    for (int r = 0; r < 4; ++r) {
      int nn = n0 + r0 + r;
      if (nn < n) {
        *(float4*)&R[(size_t)nn * 64 + jj] =
            make_float4(acc[r][0] + b0.x, acc[r][1] + b0.y, acc[r][2] + b0.z, acc[r][3] + b0.w);
        *(float4*)&R[(size_t)nn * 64 + jj + 4] =
            make_float4(acc[r][4] + b1.x, acc[r][5] + b1.y, acc[r][6] + b1.z, acc[r][7] + b1.w);
      }
    }
  }
}

// ---- fused gather + activation. One wave per node, lane j = output dim j.
// MODE 0: relu; MODE 1: relu + residual; MODE 2: plain + L2-normalize.
template <int MODE>
__global__ __launch_bounds__(256) void k_gather(
    const float* __restrict__ P, const float* __restrict__ R,
    const float* __restrict__ hres, const int* __restrict__ csr,
    const int* __restrict__ rs, const float* __restrict__ invdeg,
    float* __restrict__ hout, int n) {
  int j = threadIdx.x & 63;
  int v = (blockIdx.x << 2) + (threadIdx.x >> 6);
  if (v >= n) return;
  int beg = rs[v], end = rs[v + 1];
  float a = 0.f;
  int i = beg;
  for (; i + 1 < end; i += 2) {
    int s0 = csr[i], s1 = csr[i + 1];
    float p0 = P[(size_t)s0 * 64 + j];
    float p1 = P[(size_t)s1 * 64 + j];
    a += p0 + p1;
  }
  if (i < end) a += P[(size_t)csr[i] * 64 + j];
  float o = a * invdeg[v] + R[(size_t)v * 64 + j];
  if (MODE == 0) {
    o = fmaxf(o, 0.f);
  } else if (MODE == 1) {
    o = fmaxf(o, 0.f) + hres[(size_t)v * 64 + j];
  } else {
    float sq = o * o;
#pragma unroll
    for (int m = 1; m < 64; m <<= 1) sq += __shfl_xor(sq, m, 64);
    float nrm = fmaxf(sqrtf(sq), 1e-12f);
    o /= nrm;
  }
  hout[(size_t)v * 64 + j] = o;
}

extern "C" void kernel_launch(void* const* d_in, const int* in_sizes, int n_in,
                              void* d_out, int out_size, void* d_ws, size_t ws_size,
                              hipStream_t stream) {
  const float* x = (const float*)d_in[0];
  const unsigned int* eraw = (const unsigned int*)d_in[1];
  const float* Wl[4] = {(const float*)d_in[2], (const float*)d_in[5],
                        (const float*)d_in[8], (const float*)d_in[11]};
  const float* blv[4] = {(const float*)d_in[3], (const float*)d_in[6],
                         (const float*)d_in[9], (const float*)d_in[12]};
  const float* Wr[4] = {(const float*)d_in[4], (const float*)d_in[7],
                        (const float*)d_in[10], (const float*)d_in[13]};
  const int N = in_sizes[0] / 64;
  const int E = in_sizes[1] / 2;
  float* out = (float*)d_out;

  char* w = (char*)d_ws;
  size_t off = 0;
  int* flag = (int*)(w + off);      off = al256(off + 4);
  int* deg = (int*)(w + off);       off = al256(off + (size_t)N * 4);
  int* rs = (int*)(w + off);        off = al256(off + (size_t)(N + 1) * 4);
  int* cur = (int*)(w + off);       off = al256(off + (size_t)N * 4);
  int* csr = (int*)(w + off);       off = al256(off + (size_t)E * 4);
  float* invdeg = (float*)(w + off); off = al256(off + (size_t)N * 4);
  int* bsum = (int*)(w + off);      off = al256(off + 4096 * 4);
  float* hA = (float*)(w + off);    off = al256(off + (size_t)N * 64 * 4);
  float* P = (float*)(w + off);     off = al256(off + (size_t)N * 64 * 4);
  float* R = (float*)(w + off);     off = al256(off + (size_t)N * 64 * 4);

  hipMemsetAsync(flag, 0, 4, stream);
  hipMemsetAsync(deg, 0, (size_t)N * 4, stream);

  int eb = (E + 255) / 256;
  int nch = (N + 255) / 256;  // 391 <= 512
  k_detect<<<eb, 256, 0, stream>>>(eraw, E, flag);
  k_count<<<eb, 256, 0, stream>>>(eraw, E, flag, deg);
  k_scan1<<<nch, 256, 0, stream>>>(deg, bsum, N);
  k_scan2<<<1, 512, 0, stream>>>(bsum, nch);
  k_scan3<<<nch, 256, 0, stream>>>(deg, bsum, rs, cur, invdeg, N);
  k_fill<<<eb, 256, 0, stream>>>(eraw, E, flag, cur, csr);

  int gb = (N + 63) / 64;
  int nb4 = (N + 3) / 4;
  // Layer 1: x -> hA (relu)
  k_gemm<<<gb, 256, 0, stream>>>(x, Wl[0], Wr[0], blv[0], P, R, N);
  k_gather<0><<<nb4, 256, 0, stream>>>(P, R, nullptr, csr, rs, invdeg, hA, N);
  // Layer 2: hA -> out (relu + residual hA)
  k_gemm<<<gb, 256, 0, stream>>>(hA, Wl[1], Wr[1], blv[1], P, R, N);
  k_gather<1><<<nb4, 256, 0, stream>>>(P, R, hA, csr, rs, invdeg, out, N);
  // Layer 3: out -> hA (relu + residual out)
  k_gemm<<<gb, 256, 0, stream>>>(out, Wl[2], Wr[2], blv[2], P, R, N);
  k_gather<1><<<nb4, 256, 0, stream>>>(P, R, out, csr, rs, invdeg, hA, N);
  // Layer 4: hA -> out (no act, L2-normalize rows)
  k_gemm<<<gb, 256, 0, stream>>>(hA, Wl[3], Wr[3], blv[3], P, R, N);
  k_gather<2><<<nb4, 256, 0, stream>>>(P, R, nullptr, csr, rs, invdeg, out, N);
}

// Round 2
// 739.305 us; speedup vs baseline: 1.3821x; 1.3821x over previous
//
#include <hip/hip_runtime.h>

// GraphSAGE 4-layer encoder, N=100000 nodes, d=64, E=1.6M edges.
// Strategy:
//   1. Build CSR (by dst) once per launch: detect int32/int64 edge_index,
//      count degrees, prefix-scan, fill adjacency (int atomics only).
//   2. Per layer: GEMM pass P = h@Wl, R = h@Wr + bl  (linearity of mean:
//      mean(h[src])@Wl == mean(P[src])), then fused gather kernel:
//      h_out = act(invdeg * sum P[nbr] + R) [+residual] [L2-normalize].
// R1->R2: k_detect was 285us (100K same-address atomicOr serialized at ~3ns
// each). Now a single block samples 16K odd words -> <5us.

static inline size_t al256(size_t x) { return (x + 255) & ~(size_t)255; }

// ---- edge dtype detection: int64 little-endian values < 2^31 have all odd
// 32-bit words zero. flag=1 -> int32, flag=0 -> int64.
// Single block, 16384 samples: P(all sampled int32 node-ids == 0) ~ 0.
__global__ void k_detect(const unsigned int* __restrict__ raw, int E, int* __restrict__ flag) {
  int nz = 0;
#pragma unroll
  for (int k = 0; k < 64; ++k) {
    int i = threadIdx.x + (k << 8);
    if (i < E && raw[2 * i + 1] != 0u) nz = 1;
  }
  unsigned long long b = __ballot(nz != 0);
  if ((threadIdx.x & 63) == 0 && b) atomicOr(flag, 1);
}

__global__ void k_count(const unsigned int* __restrict__ raw, int E,
                        const int* __restrict__ flag, int* __restrict__ deg) {
  int i = blockIdx.x * 256 + threadIdx.x;
  if (i >= E) return;
  int f = *flag;
  int dst = f ? (int)raw[E + i] : (int)raw[2 * (E + i)];
  atomicAdd(&deg[dst], 1);
}

__global__ void k_scan1(const int* __restrict__ deg, int* __restrict__ bsum, int n) {
  int i = blockIdx.x * 256 + threadIdx.x;
  int v = (i < n) ? deg[i] : 0;
#pragma unroll
  for (int m = 1; m < 64; m <<= 1) v += __shfl_xor(v, m, 64);
  __shared__ int ls[4];
  if ((threadIdx.x & 63) == 0) ls[threadIdx.x >> 6] = v;
  __syncthreads();
  if (threadIdx.x == 0) bsum[blockIdx.x] = ls[0] + ls[1] + ls[2] + ls[3];
}

__global__ void k_scan2(int* __restrict__ bsum, int nch) {
  __shared__ int s[512];
  int t = threadIdx.x;
  int v = (t < nch) ? bsum[t] : 0;
  s[t] = v;
  __syncthreads();
  for (int off = 1; off < 512; off <<= 1) {
    int add = (t >= off) ? s[t - off] : 0;
    __syncthreads();
    s[t] += add;
    __syncthreads();
  }
  if (t < nch) bsum[t] = s[t] - v;  // exclusive
}

__global__ void k_scan3(const int* __restrict__ deg, const int* __restrict__ bsum,
                        int* __restrict__ rs, int* __restrict__ cursor,
                        float* __restrict__ invdeg, int n) {
  __shared__ int s[256];
  int t = threadIdx.x;
  int i = blockIdx.x * 256 + t;
  int d = (i < n) ? deg[i] : 0;
  s[t] = d;
  __syncthreads();
  for (int off = 1; off < 256; off <<= 1) {
    int add = (t >= off) ? s[t - off] : 0;
    __syncthreads();
    s[t] += add;
    __syncthreads();
  }
  int ex = s[t] - d + bsum[blockIdx.x];
  if (i < n) {
    rs[i] = ex;
    cursor[i] = ex;
    invdeg[i] = 1.0f / fmaxf((float)d, 1.0f);
    if (i == n - 1) rs[n] = ex + d;
  }
}

__global__ void k_fill(const unsigned int* __restrict__ raw, int E,
                       const int* __restrict__ flag, int* __restrict__ cursor,
                       int* __restrict__ csr) {
  int i = blockIdx.x * 256 + threadIdx.x;
  if (i >= E) return;
  int f = *flag;
  int src = f ? (int)raw[i] : (int)raw[2 * i];
  int dst = f ? (int)raw[E + i] : (int)raw[2 * (E + i)];
  int pos = atomicAdd(&cursor[dst], 1);
  csr[pos] = src;
}

// ---- GEMM: P = h @ Wl ; R = h @ Wr + bl.  Block tile: 64 nodes x 128 cols.
// 256 threads, each computes 4 rows x 8 cols of the concatenated [Wl|Wr].
__global__ __launch_bounds__(256) void k_gemm(
    const float* __restrict__ h, const float* __restrict__ Wl,
    const float* __restrict__ Wr, const float* __restrict__ bl,
    float* __restrict__ P, float* __restrict__ R, int n) {
  __shared__ float hT[64][68];   // transposed h tile, padded: 16B-aligned float4 rows
  __shared__ float W2[64][128];  // [k][j]: j<64 -> Wl, else Wr
  int t = threadIdx.x;
  int n0 = blockIdx.x * 64;

  for (int idx = t; idx < 64 * 128; idx += 256) {
    int k = idx >> 7, j = idx & 127;
    W2[k][j] = (j < 64) ? Wl[k * 64 + j] : Wr[k * 64 + (j - 64)];
  }
  for (int idx = t; idx < 64 * 16; idx += 256) {
    int r = idx >> 4;
    int k4 = (idx & 15) * 4;
    int nn = n0 + r;
    float4 hv = (nn < n) ? *(const float4*)&h[(size_t)nn * 64 + k4]
                         : make_float4(0.f, 0.f, 0.f, 0.f);
    hT[k4 + 0][r] = hv.x;
    hT[k4 + 1][r] = hv.y;
    hT[k4 + 2][r] = hv.z;
    hT[k4 + 3][r] = hv.w;
  }
  __syncthreads();

  int j0 = (t & 15) * 8;
  int r0 = (t >> 4) * 4;
  float acc[4][8] = {};
#pragma unroll 8
  for (int k = 0; k < 64; ++k) {
    float4 hv = *(const float4*)&hT[k][r0];
    float wv[8];
    *(float4*)&wv[0] = *(const float4*)&W2[k][j0];
    *(float4*)&wv[4] = *(const float4*)&W2[k][j0 + 4];
    float hr[4] = {hv.x, hv.y, hv.z, hv.w};
#pragma unroll
    for (int r = 0; r < 4; ++r)
#pragma unroll
      for (int c = 0; c < 8; ++c) acc[r][c] = fmaf(hr[r], wv[c], acc[r][c]);
  }

  if (j0 < 64) {
#pragma unroll
    for (int r = 0; r < 4; ++r) {
      int nn = n0 + r0 + r;
      if (nn < n) {
        *(float4*)&P[(size_t)nn * 64 + j0] = make_float4(acc[r][0], acc[r][1], acc[r][2], acc[r][3]);
        *(float4*)&P[(size_t)nn * 64 + j0 + 4] = make_float4(acc[r][4], acc[r][5], acc[r][6], acc[r][7]);
      }
    }
  } else {
    int jj = j0 - 64;
    float4 b0 = *(const float4*)&bl[jj];
    float4 b1 = *(const float4*)&bl[jj + 4];
#pragma unroll
    for (int r = 0; r < 4; ++r) {
      int nn = n0 + r0 + r;
      if (nn < n) {
        *(float4*)&R[(size_t)nn * 64 + jj] =
            make_float4(acc[r][0] + b0.x, acc[r][1] + b0.y, acc[r][2] + b0.z, acc[r][3] + b0.w);
        *(float4*)&R[(size_t)nn * 64 + jj + 4] =
            make_float4(acc[r][4] + b1.x, acc[r][5] + b1.y, acc[r][6] + b1.z, acc[r][7] + b1.w);
      }
    }
  }
}

// ---- fused gather + activation. One wave per node, lane j = output dim j.
// MODE 0: relu; MODE 1: relu + residual; MODE 2: plain + L2-normalize.
template <int MODE>
__global__ __launch_bounds__(256) void k_gather(
    const float* __restrict__ P, const float* __restrict__ R,
    const float* __restrict__ hres, const int* __restrict__ csr,
    const int* __restrict__ rs, const float* __restrict__ invdeg,
    float* __restrict__ hout, int n) {
  int j = threadIdx.x & 63;
  int v = (blockIdx.x << 2) + (threadIdx.x >> 6);
  if (v >= n) return;
  int beg = rs[v], end = rs[v + 1];
  float a = 0.f;
  int i = beg;
  for (; i + 1 < end; i += 2) {
    int s0 = csr[i], s1 = csr[i + 1];
    float p0 = P[(size_t)s0 * 64 + j];
    float p1 = P[(size_t)s1 * 64 + j];
    a += p0 + p1;
  }
  if (i < end) a += P[(size_t)csr[i] * 64 + j];
  float o = a * invdeg[v] + R[(size_t)v * 64 + j];
  if (MODE == 0) {
    o = fmaxf(o, 0.f);
  } else if (MODE == 1) {
    o = fmaxf(o, 0.f) + hres[(size_t)v * 64 + j];
  } else {
    float sq = o * o;
#pragma unroll
    for (int m = 1; m < 64; m <<= 1) sq += __shfl_xor(sq, m, 64);
    float nrm = fmaxf(sqrtf(sq), 1e-12f);
    o /= nrm;
  }
  hout[(size_t)v * 64 + j] = o;
}

extern "C" void kernel_launch(void* const* d_in, const int* in_sizes, int n_in,
                              void* d_out, int out_size, void* d_ws, size_t ws_size,
                              hipStream_t stream) {
  const float* x = (const float*)d_in[0];
  const unsigned int* eraw = (const unsigned int*)d_in[1];
  const float* Wl[4] = {(const float*)d_in[2], (const float*)d_in[5],
                        (const float*)d_in[8], (const float*)d_in[11]};
  const float* blv[4] = {(const float*)d_in[3], (const float*)d_in[6],
                         (const float*)d_in[9], (const float*)d_in[12]};
  const float* Wr[4] = {(const float*)d_in[4], (const float*)d_in[7],
                        (const float*)d_in[10], (const float*)d_in[13]};
  const int N = in_sizes[0] / 64;
  const int E = in_sizes[1] / 2;
  float* out = (float*)d_out;

  char* w = (char*)d_ws;
  size_t off = 0;
  int* flag = (int*)(w + off);      off = al256(off + 4);
  int* deg = (int*)(w + off);       off = al256(off + (size_t)N * 4);
  int* rs = (int*)(w + off);        off = al256(off + (size_t)(N + 1) * 4);
  int* cur = (int*)(w + off);       off = al256(off + (size_t)N * 4);
  int* csr = (int*)(w + off);       off = al256(off + (size_t)E * 4);
  float* invdeg = (float*)(w + off); off = al256(off + (size_t)N * 4);
  int* bsum = (int*)(w + off);      off = al256(off + 4096 * 4);
  float* hA = (float*)(w + off);    off = al256(off + (size_t)N * 64 * 4);
  float* P = (float*)(w + off);     off = al256(off + (size_t)N * 64 * 4);
  float* R = (float*)(w + off);     off = al256(off + (size_t)N * 64 * 4);

  hipMemsetAsync(flag, 0, 4, stream);
  hipMemsetAsync(deg, 0, (size_t)N * 4, stream);

  int eb = (E + 255) / 256;
  int nch = (N + 255) / 256;  // 391 <= 512
  k_detect<<<1, 256, 0, stream>>>(eraw, E, flag);
  k_count<<<eb, 256, 0, stream>>>(eraw, E, flag, deg);
  k_scan1<<<nch, 256, 0, stream>>>(deg, bsum, N);
  k_scan2<<<1, 512, 0, stream>>>(bsum, nch);
  k_scan3<<<nch, 256, 0, stream>>>(deg, bsum, rs, cur, invdeg, N);
  k_fill<<<eb, 256, 0, stream>>>(eraw, E, flag, cur, csr);

  int gb = (N + 63) / 64;
  int nb4 = (N + 3) / 4;
  // Layer 1: x -> hA (relu)
  k_gemm<<<gb, 256, 0, stream>>>(x, Wl[0], Wr[0], blv[0], P, R, N);
  k_gather<0><<<nb4, 256, 0, stream>>>(P, R, nullptr, csr, rs, invdeg, hA, N);
  // Layer 2: hA -> out (relu + residual hA)
  k_gemm<<<gb, 256, 0, stream>>>(hA, Wl[1], Wr[1], blv[1], P, R, N);
  k_gather<1><<<nb4, 256, 0, stream>>>(P, R, hA, csr, rs, invdeg, out, N);
  // Layer 3: out -> hA (relu + residual out)
  k_gemm<<<gb, 256, 0, stream>>>(out, Wl[2], Wr[2], blv[2], P, R, N);
  k_gather<1><<<nb4, 256, 0, stream>>>(P, R, out, csr, rs, invdeg, hA, N);
  // Layer 4: hA -> out (no act, L2-normalize rows)
  k_gemm<<<gb, 256, 0, stream>>>(hA, Wl[3], Wr[3], blv[3], P, R, N);
  k_gather<2><<<nb4, 256, 0, stream>>>(P, R, nullptr, csr, rs, invdeg, out, N);
}

// Round 3
// 607.598 us; speedup vs baseline: 1.6817x; 1.2168x over previous
//
#include <hip/hip_runtime.h>

// GraphSAGE 4-layer encoder, N=100000 nodes, d=64, E=1.6M edges.
//   1. CSR build via 2-level bucket sort (R3): bucket = dst/span (256 buckets),
//      LDS histograms + per-(block,bucket) reservations -> no per-node global
//      atomics, no scattered-write line thrash (R2 k_fill had 16x write amp).
//   2. Per layer: GEMM pass P = h@Wl, R = h@Wr + bl  (linearity of mean:
//      mean(h[src])@Wl == mean(P[src])), then fused gather kernel:
//      h_out = act(invdeg * sum P[nbr] + R) [+residual] [L2-normalize].

static inline size_t al256(size_t x) { return (x + 255) & ~(size_t)255; }

#define EPB 8192  // edges per block in bucket passes

// ---- edge dtype detection: int64 little-endian values < 2^31 have all odd
// 32-bit words zero. flag=1 -> int32, flag=0 -> int64. Single block samples
// 16384 odd words: P(false int64 verdict on random int32 ids) ~ 0.
__global__ void k_detect(const unsigned int* __restrict__ raw, int E, int* __restrict__ flag) {
  int nz = 0;
#pragma unroll
  for (int k = 0; k < 64; ++k) {
    int i = threadIdx.x + (k << 8);
    if (i < E && raw[2 * (size_t)i + 1] != 0u) nz = 1;
  }
  unsigned long long b = __ballot(nz != 0);
  if ((threadIdx.x & 63) == 0 && b) atomicOr(flag, 1);
}

// ---- pass A: bucket counts via LDS histogram.
__global__ __launch_bounds__(256) void k_bcount(const unsigned int* __restrict__ raw, int E,
                                                int span, const int* __restrict__ flag,
                                                int* __restrict__ bucketCount) {
  __shared__ int lh[256];
  int t = threadIdx.x;
  lh[t] = 0;
  __syncthreads();
  int f = *flag;
  int base = blockIdx.x * EPB;
#pragma unroll 4
  for (int k = 0; k < EPB / 256; ++k) {
    int i = base + k * 256 + t;
    if (i < E) {
      int dst = f ? (int)raw[E + i] : (int)raw[2 * (size_t)(E + i)];
      atomicAdd(&lh[dst / span], 1);
    }
  }
  __syncthreads();
  int c = lh[t];
  if (c) atomicAdd(&bucketCount[t], c);
}

// ---- scan 256 bucket counts -> boff[257], init cursorB, rs[N]=E.
__global__ void k_bscan(const int* __restrict__ bucketCount, int* __restrict__ boff,
                        int* __restrict__ cursorB, int* __restrict__ rs, int N, int E) {
  __shared__ int sa[256], sb[256];
  int t = threadIdx.x;
  int v = bucketCount[t];
  sa[t] = v;
  __syncthreads();
  int* s = sa;
  int* d = sb;
  for (int off = 1; off < 256; off <<= 1) {
    d[t] = s[t] + (t >= off ? s[t - off] : 0);
    __syncthreads();
    int* tmp = s; s = d; d = tmp;
  }
  int inc = s[t];
  int ex = inc - v;
  boff[t] = ex;
  cursorB[t] = ex;
  if (t == 255) boff[256] = inc;
  if (t == 0) rs[N] = E;
}

// ---- pass B: scatter (src,dst) pairs into bucket-contiguous bdata.
__global__ __launch_bounds__(256) void k_bscatter(const unsigned int* __restrict__ raw, int E,
                                                  int span, const int* __restrict__ flag,
                                                  int* __restrict__ cursorB,
                                                  uint2* __restrict__ bdata) {
  __shared__ int lh[256], lcur[256], gbase[256];
  int t = threadIdx.x;
  lh[t] = 0;
  lcur[t] = 0;
  __syncthreads();
  int f = *flag;
  int base = blockIdx.x * EPB;
#pragma unroll 4
  for (int k = 0; k < EPB / 256; ++k) {
    int i = base + k * 256 + t;
    if (i < E) {
      int dst = f ? (int)raw[E + i] : (int)raw[2 * (size_t)(E + i)];
      atomicAdd(&lh[dst / span], 1);
    }
  }
  __syncthreads();
  int c = lh[t];
  gbase[t] = c ? atomicAdd(&cursorB[t], c) : 0;
  __syncthreads();
#pragma unroll 4
  for (int k = 0; k < EPB / 256; ++k) {
    int i = base + k * 256 + t;
    if (i < E) {
      int s_, d_;
      if (f) { s_ = (int)raw[i]; d_ = (int)raw[E + i]; }
      else   { s_ = (int)raw[2 * (size_t)i]; d_ = (int)raw[2 * (size_t)(E + i)]; }
      int b = d_ / span;
      int pos = atomicAdd(&lcur[b], 1);
      bdata[(size_t)gbase[b] + pos] = make_uint2((unsigned)s_, (unsigned)d_);
    }
  }
}

// ---- pass C: one block per bucket. Node histogram + scan in LDS, write
// rs/invdeg, scatter src ids into the bucket's contiguous csr window.
// Requires span <= 512 (N <= 131072).
__global__ __launch_bounds__(256) void k_bbuild(const uint2* __restrict__ bdata,
                                                const int* __restrict__ boff, int span, int N,
                                                int* __restrict__ csr, int* __restrict__ rs,
                                                float* __restrict__ invdeg) {
  __shared__ int cnt[512], sa[512], sb[512], cur[512];
  int b = blockIdx.x;
  int t = threadIdx.x;
  int node0 = b * span;
  int beg = boff[b], end = boff[b + 1];
  cnt[t] = 0;
  cnt[t + 256] = 0;
  __syncthreads();
  for (int i = beg + t; i < end; i += 256) {
    int d = (int)bdata[i].y - node0;
    atomicAdd(&cnt[d], 1);
  }
  __syncthreads();
  // inclusive scan of cnt[0..512) with 256 threads, ping-pong
  sa[t] = cnt[t];
  sa[t + 256] = cnt[t + 256];
  __syncthreads();
  int* s = sa;
  int* d = sb;
  for (int off = 1; off < 512; off <<= 1) {
    d[t] = s[t] + (t >= off ? s[t - off] : 0);
    int i2 = t + 256;
    d[i2] = s[i2] + (i2 >= off ? s[i2 - off] : 0);
    __syncthreads();
    int* tmp = s; s = d; d = tmp;
  }
  // exclusive offsets -> cur; write rs/invdeg before cur is consumed
  int ex0 = s[t] - cnt[t];
  int ex1 = s[t + 256] - cnt[t + 256];
  cur[t] = ex0;
  cur[t + 256] = ex1;
  if (t < span) {
    int node = node0 + t;
    if (node < N) {
      rs[node] = beg + ex0;
      invdeg[node] = 1.0f / fmaxf((float)cnt[t], 1.0f);
    }
  }
  int t2 = t + 256;
  if (t2 < span) {
    int node = node0 + t2;
    if (node < N) {
      rs[node] = beg + ex1;
      invdeg[node] = 1.0f / fmaxf((float)cnt[t2], 1.0f);
    }
  }
  __syncthreads();
  for (int i = beg + t; i < end; i += 256) {
    uint2 p = bdata[i];
    int dd = (int)p.y - node0;
    int pos = atomicAdd(&cur[dd], 1);
    csr[beg + pos] = (int)p.x;
  }
}

// ---- GEMM: P = h @ Wl ; R = h @ Wr + bl.  Block tile: 64 nodes x 128 cols.
// 256 threads, each computes 4 rows x 8 cols of the concatenated [Wl|Wr].
__global__ __launch_bounds__(256) void k_gemm(
    const float* __restrict__ h, const float* __restrict__ Wl,
    const float* __restrict__ Wr, const float* __restrict__ bl,
    float* __restrict__ P, float* __restrict__ R, int n) {
  __shared__ float hT[64][68];   // transposed h tile, padded
  __shared__ float W2[64][128];  // [k][j]: j<64 -> Wl, else Wr
  int t = threadIdx.x;
  int n0 = blockIdx.x * 64;

  for (int idx = t; idx < 64 * 128; idx += 256) {
    int k = idx >> 7, j = idx & 127;
    W2[k][j] = (j < 64) ? Wl[k * 64 + j] : Wr[k * 64 + (j - 64)];
  }
  for (int idx = t; idx < 64 * 16; idx += 256) {
    int r = idx >> 4;
    int k4 = (idx & 15) * 4;
    int nn = n0 + r;
    float4 hv = (nn < n) ? *(const float4*)&h[(size_t)nn * 64 + k4]
                         : make_float4(0.f, 0.f, 0.f, 0.f);
    hT[k4 + 0][r] = hv.x;
    hT[k4 + 1][r] = hv.y;
    hT[k4 + 2][r] = hv.z;
    hT[k4 + 3][r] = hv.w;
  }
  __syncthreads();

  int j0 = (t & 15) * 8;
  int r0 = (t >> 4) * 4;
  float acc[4][8] = {};
#pragma unroll 8
  for (int k = 0; k < 64; ++k) {
    float4 hv = *(const float4*)&hT[k][r0];
    float wv[8];
    *(float4*)&wv[0] = *(const float4*)&W2[k][j0];
    *(float4*)&wv[4] = *(const float4*)&W2[k][j0 + 4];
    float hr[4] = {hv.x, hv.y, hv.z, hv.w};
#pragma unroll
    for (int r = 0; r < 4; ++r)
#pragma unroll
      for (int c = 0; c < 8; ++c) acc[r][c] = fmaf(hr[r], wv[c], acc[r][c]);
  }

  if (j0 < 64) {
#pragma unroll
    for (int r = 0; r < 4; ++r) {
      int nn = n0 + r0 + r;
      if (nn < n) {
        *(float4*)&P[(size_t)nn * 64 + j0] = make_float4(acc[r][0], acc[r][1], acc[r][2], acc[r][3]);
        *(float4*)&P[(size_t)nn * 64 + j0 + 4] = make_float4(acc[r][4], acc[r][5], acc[r][6], acc[r][7]);
      }
    }
  } else {
    int jj = j0 - 64;
    float4 b0 = *(const float4*)&bl[jj];
    float4 b1 = *(const float4*)&bl[jj + 4];
#pragma unroll
    for (int r = 0; r < 4; ++r) {
      int nn = n0 + r0 + r;
      if (nn < n) {
        *(float4*)&R[(size_t)nn * 64 + jj] =
            make_float4(acc[r][0] + b0.x, acc[r][1] + b0.y, acc[r][2] + b0.z, acc[r][3] + b0.w);
        *(float4*)&R[(size_t)nn * 64 + jj + 4] =
            make_float4(acc[r][4] + b1.x, acc[r][5] + b1.y, acc[r][6] + b1.z, acc[r][7] + b1.w);
      }
    }
  }
}

// ---- fused gather + activation. One wave per node, lane j = output dim j.
// MODE 0: relu; MODE 1: relu + residual; MODE 2: plain + L2-normalize.
template <int MODE>
__global__ __launch_bounds__(256) void k_gather(
    const float* __restrict__ P, const float* __restrict__ R,
    const float* __restrict__ hres, const int* __restrict__ csr,
    const int* __restrict__ rs, const float* __restrict__ invdeg,
    float* __restrict__ hout, int n) {
  int j = threadIdx.x & 63;
  int v = (blockIdx.x << 2) + (threadIdx.x >> 6);
  if (v >= n) return;
  int beg = rs[v], end = rs[v + 1];
  float a = 0.f;
  int i = beg;
  for (; i + 1 < end; i += 2) {
    int s0 = csr[i], s1 = csr[i + 1];
    float p0 = P[(size_t)s0 * 64 + j];
    float p1 = P[(size_t)s1 * 64 + j];
    a += p0 + p1;
  }
  if (i < end) a += P[(size_t)csr[i] * 64 + j];
  float o = a * invdeg[v] + R[(size_t)v * 64 + j];
  if (MODE == 0) {
    o = fmaxf(o, 0.f);
  } else if (MODE == 1) {
    o = fmaxf(o, 0.f) + hres[(size_t)v * 64 + j];
  } else {
    float sq = o * o;
#pragma unroll
    for (int m = 1; m < 64; m <<= 1) sq += __shfl_xor(sq, m, 64);
    float nrm = fmaxf(sqrtf(sq), 1e-12f);
    o /= nrm;
  }
  hout[(size_t)v * 64 + j] = o;
}

extern "C" void kernel_launch(void* const* d_in, const int* in_sizes, int n_in,
                              void* d_out, int out_size, void* d_ws, size_t ws_size,
                              hipStream_t stream) {
  const float* x = (const float*)d_in[0];
  const unsigned int* eraw = (const unsigned int*)d_in[1];
  const float* Wl[4] = {(const float*)d_in[2], (const float*)d_in[5],
                        (const float*)d_in[8], (const float*)d_in[11]};
  const float* blv[4] = {(const float*)d_in[3], (const float*)d_in[6],
                         (const float*)d_in[9], (const float*)d_in[12]};
  const float* Wr[4] = {(const float*)d_in[4], (const float*)d_in[7],
                        (const float*)d_in[10], (const float*)d_in[13]};
  const int N = in_sizes[0] / 64;
  const int E = in_sizes[1] / 2;
  const int span = (N + 255) / 256;  // nodes per bucket; must be <= 512
  float* out = (float*)d_out;

  char* w = (char*)d_ws;
  size_t off = 0;
  int* flag = (int*)(w + off);        off = al256(off + 4);
  int* bucketCount = (int*)(w + off); off = al256(off + 256 * 4);
  int* boff = (int*)(w + off);        off = al256(off + 257 * 4);
  int* cursorB = (int*)(w + off);     off = al256(off + 256 * 4);
  int* csr = (int*)(w + off);         off = al256(off + (size_t)E * 4);
  float* invdeg = (float*)(w + off);  off = al256(off + (size_t)N * 4);
  int* rs = (int*)(w + off);          off = al256(off + (size_t)(N + 1) * 4);
  uint2* bdata = (uint2*)(w + off);   off = al256(off + (size_t)E * 8);
  float* hA = (float*)(w + off);      off = al256(off + (size_t)N * 64 * 4);
  float* P = (float*)(w + off);       off = al256(off + (size_t)N * 64 * 4);
  float* R = (float*)(w + off);       off = al256(off + (size_t)N * 64 * 4);

  hipMemsetAsync(flag, 0, 4, stream);
  hipMemsetAsync(bucketCount, 0, 256 * 4, stream);

  int eb = (E + EPB - 1) / EPB;
  k_detect<<<1, 256, 0, stream>>>(eraw, E, flag);
  k_bcount<<<eb, 256, 0, stream>>>(eraw, E, span, flag, bucketCount);
  k_bscan<<<1, 256, 0, stream>>>(bucketCount, boff, cursorB, rs, N, E);
  k_bscatter<<<eb, 256, 0, stream>>>(eraw, E, span, flag, cursorB, bdata);
  k_bbuild<<<256, 256, 0, stream>>>(bdata, boff, span, N, csr, rs, invdeg);

  int gb = (N + 63) / 64;
  int nb4 = (N + 3) / 4;
  // Layer 1: x -> hA (relu)
  k_gemm<<<gb, 256, 0, stream>>>(x, Wl[0], Wr[0], blv[0], P, R, N);
  k_gather<0><<<nb4, 256, 0, stream>>>(P, R, nullptr, csr, rs, invdeg, hA, N);
  // Layer 2: hA -> out (relu + residual hA)
  k_gemm<<<gb, 256, 0, stream>>>(hA, Wl[1], Wr[1], blv[1], P, R, N);
  k_gather<1><<<nb4, 256, 0, stream>>>(P, R, hA, csr, rs, invdeg, out, N);
  // Layer 3: out -> hA (relu + residual out)
  k_gemm<<<gb, 256, 0, stream>>>(out, Wl[2], Wr[2], blv[2], P, R, N);
  k_gather<1><<<nb4, 256, 0, stream>>>(P, R, out, csr, rs, invdeg, hA, N);
  // Layer 4: hA -> out (no act, L2-normalize rows)
  k_gemm<<<gb, 256, 0, stream>>>(hA, Wl[3], Wr[3], blv[3], P, R, N);
  k_gather<2><<<nb4, 256, 0, stream>>>(P, R, nullptr, csr, rs, invdeg, out, N);
}

// Round 4
// 587.783 us; speedup vs baseline: 1.7384x; 1.0337x over previous
//
#include <hip/hip_runtime.h>

// GraphSAGE 4-layer encoder, N=100000 nodes, d=64, E=1.6M edges.
//   1. CSR build via 2-level bucket sort: bucket = dst/span (256 buckets),
//      LDS histograms + per-(block,bucket) reservations -> no per-node global
//      atomics, no scattered-write line thrash.
//   2. Per layer: GEMM pass P = h@Wl (stored bf16), R = h@Wr + bl (f32)
//      (linearity of mean: mean(h[src])@Wl == mean(P[src])), then fused
//      gather: h_out = act(invdeg * sum P[nbr] + R) [+residual] [L2-norm].
// R3->R4: gather was L2-capacity-miss bound (193MB fetch vs 25.6MB P).
// P in bf16 halves the random-access working set (12.8MB) and traffic.

#include <hip/hip_bf16.h>

static inline size_t al256(size_t x) { return (x + 255) & ~(size_t)255; }

#define EPB 8192  // edges per block in bucket passes

__device__ inline unsigned short f2bf(float f) {
  unsigned u = __float_as_uint(f);
  return (unsigned short)((u + 0x7fffu + ((u >> 16) & 1u)) >> 16);  // RNE
}

// ---- edge dtype detection: int64 little-endian values < 2^31 have all odd
// 32-bit words zero. flag=1 -> int32, flag=0 -> int64. Single block samples
// 16384 odd words.
__global__ void k_detect(const unsigned int* __restrict__ raw, int E, int* __restrict__ flag) {
  int nz = 0;
#pragma unroll
  for (int k = 0; k < 64; ++k) {
    int i = threadIdx.x + (k << 8);
    if (i < E && raw[2 * (size_t)i + 1] != 0u) nz = 1;
  }
  unsigned long long b = __ballot(nz != 0);
  if ((threadIdx.x & 63) == 0 && b) atomicOr(flag, 1);
}

// ---- pass A: bucket counts via LDS histogram.
__global__ __launch_bounds__(256) void k_bcount(const unsigned int* __restrict__ raw, int E,
                                                int span, const int* __restrict__ flag,
                                                int* __restrict__ bucketCount) {
  __shared__ int lh[256];
  int t = threadIdx.x;
  lh[t] = 0;
  __syncthreads();
  int f = *flag;
  int base = blockIdx.x * EPB;
#pragma unroll 4
  for (int k = 0; k < EPB / 256; ++k) {
    int i = base + k * 256 + t;
    if (i < E) {
      int dst = f ? (int)raw[E + i] : (int)raw[2 * (size_t)(E + i)];
      atomicAdd(&lh[dst / span], 1);
    }
  }
  __syncthreads();
  int c = lh[t];
  if (c) atomicAdd(&bucketCount[t], c);
}

// ---- scan 256 bucket counts -> boff[257], init cursorB, rs[N]=E.
__global__ void k_bscan(const int* __restrict__ bucketCount, int* __restrict__ boff,
                        int* __restrict__ cursorB, int* __restrict__ rs, int N, int E) {
  __shared__ int sa[256], sb[256];
  int t = threadIdx.x;
  int v = bucketCount[t];
  sa[t] = v;
  __syncthreads();
  int* s = sa;
  int* d = sb;
  for (int off = 1; off < 256; off <<= 1) {
    d[t] = s[t] + (t >= off ? s[t - off] : 0);
    __syncthreads();
    int* tmp = s; s = d; d = tmp;
  }
  int inc = s[t];
  int ex = inc - v;
  boff[t] = ex;
  cursorB[t] = ex;
  if (t == 255) boff[256] = inc;
  if (t == 0) rs[N] = E;
}

// ---- pass B: scatter (src,dst) pairs into bucket-contiguous bdata.
__global__ __launch_bounds__(256) void k_bscatter(const unsigned int* __restrict__ raw, int E,
                                                  int span, const int* __restrict__ flag,
                                                  int* __restrict__ cursorB,
                                                  uint2* __restrict__ bdata) {
  __shared__ int lh[256], lcur[256], gbase[256];
  int t = threadIdx.x;
  lh[t] = 0;
  lcur[t] = 0;
  __syncthreads();
  int f = *flag;
  int base = blockIdx.x * EPB;
#pragma unroll 4
  for (int k = 0; k < EPB / 256; ++k) {
    int i = base + k * 256 + t;
    if (i < E) {
      int dst = f ? (int)raw[E + i] : (int)raw[2 * (size_t)(E + i)];
      atomicAdd(&lh[dst / span], 1);
    }
  }
  __syncthreads();
  int c = lh[t];
  gbase[t] = c ? atomicAdd(&cursorB[t], c) : 0;
  __syncthreads();
#pragma unroll 4
  for (int k = 0; k < EPB / 256; ++k) {
    int i = base + k * 256 + t;
    if (i < E) {
      int s_, d_;
      if (f) { s_ = (int)raw[i]; d_ = (int)raw[E + i]; }
      else   { s_ = (int)raw[2 * (size_t)i]; d_ = (int)raw[2 * (size_t)(E + i)]; }
      int b = d_ / span;
      int pos = atomicAdd(&lcur[b], 1);
      bdata[(size_t)gbase[b] + pos] = make_uint2((unsigned)s_, (unsigned)d_);
    }
  }
}

// ---- pass C: one block per bucket. Node histogram + scan in LDS, write
// rs/invdeg, scatter src ids into the bucket's contiguous csr window.
// Requires span <= 512 (N <= 131072).
__global__ __launch_bounds__(256) void k_bbuild(const uint2* __restrict__ bdata,
                                                const int* __restrict__ boff, int span, int N,
                                                int* __restrict__ csr, int* __restrict__ rs,
                                                float* __restrict__ invdeg) {
  __shared__ int cnt[512], sa[512], sb[512], cur[512];
  int b = blockIdx.x;
  int t = threadIdx.x;
  int node0 = b * span;
  int beg = boff[b], end = boff[b + 1];
  cnt[t] = 0;
  cnt[t + 256] = 0;
  __syncthreads();
  for (int i = beg + t; i < end; i += 256) {
    int d = (int)bdata[i].y - node0;
    atomicAdd(&cnt[d], 1);
  }
  __syncthreads();
  sa[t] = cnt[t];
  sa[t + 256] = cnt[t + 256];
  __syncthreads();
  int* s = sa;
  int* d = sb;
  for (int off = 1; off < 512; off <<= 1) {
    d[t] = s[t] + (t >= off ? s[t - off] : 0);
    int i2 = t + 256;
    d[i2] = s[i2] + (i2 >= off ? s[i2 - off] : 0);
    __syncthreads();
    int* tmp = s; s = d; d = tmp;
  }
  int ex0 = s[t] - cnt[t];
  int ex1 = s[t + 256] - cnt[t + 256];
  cur[t] = ex0;
  cur[t + 256] = ex1;
  if (t < span) {
    int node = node0 + t;
    if (node < N) {
      rs[node] = beg + ex0;
      invdeg[node] = 1.0f / fmaxf((float)cnt[t], 1.0f);
    }
  }
  int t2 = t + 256;
  if (t2 < span) {
    int node = node0 + t2;
    if (node < N) {
      rs[node] = beg + ex1;
      invdeg[node] = 1.0f / fmaxf((float)cnt[t2], 1.0f);
    }
  }
  __syncthreads();
  for (int i = beg + t; i < end; i += 256) {
    uint2 p = bdata[i];
    int dd = (int)p.y - node0;
    int pos = atomicAdd(&cur[dd], 1);
    csr[beg + pos] = (int)p.x;
  }
}

// ---- GEMM: P(bf16) = h @ Wl ; R(f32) = h @ Wr + bl. Tile 64 nodes x 128 cols.
__global__ __launch_bounds__(256) void k_gemm(
    const float* __restrict__ h, const float* __restrict__ Wl,
    const float* __restrict__ Wr, const float* __restrict__ bl,
    unsigned short* __restrict__ Pb, float* __restrict__ R, int n) {
  __shared__ float hT[64][68];   // transposed h tile, padded
  __shared__ float W2[64][128];  // [k][j]: j<64 -> Wl, else Wr
  int t = threadIdx.x;
  int n0 = blockIdx.x * 64;

  for (int idx = t; idx < 64 * 128; idx += 256) {
    int k = idx >> 7, j = idx & 127;
    W2[k][j] = (j < 64) ? Wl[k * 64 + j] : Wr[k * 64 + (j - 64)];
  }
  for (int idx = t; idx < 64 * 16; idx += 256) {
    int r = idx >> 4;
    int k4 = (idx & 15) * 4;
    int nn = n0 + r;
    float4 hv = (nn < n) ? *(const float4*)&h[(size_t)nn * 64 + k4]
                         : make_float4(0.f, 0.f, 0.f, 0.f);
    hT[k4 + 0][r] = hv.x;
    hT[k4 + 1][r] = hv.y;
    hT[k4 + 2][r] = hv.z;
    hT[k4 + 3][r] = hv.w;
  }
  __syncthreads();

  int j0 = (t & 15) * 8;
  int r0 = (t >> 4) * 4;
  float acc[4][8] = {};
#pragma unroll 8
  for (int k = 0; k < 64; ++k) {
    float4 hv = *(const float4*)&hT[k][r0];
    float wv[8];
    *(float4*)&wv[0] = *(const float4*)&W2[k][j0];
    *(float4*)&wv[4] = *(const float4*)&W2[k][j0 + 4];
    float hr[4] = {hv.x, hv.y, hv.z, hv.w};
#pragma unroll
    for (int r = 0; r < 4; ++r)
#pragma unroll
      for (int c = 0; c < 8; ++c) acc[r][c] = fmaf(hr[r], wv[c], acc[r][c]);
  }

  if (j0 < 64) {
#pragma unroll
    for (int r = 0; r < 4; ++r) {
      int nn = n0 + r0 + r;
      if (nn < n) {
        union { unsigned short us[8]; uint4 u4; } pk;
#pragma unroll
        for (int c = 0; c < 8; ++c) pk.us[c] = f2bf(acc[r][c]);
        *(uint4*)&Pb[(size_t)nn * 64 + j0] = pk.u4;  // j0*2 bytes: 16B aligned
      }
    }
  } else {
    int jj = j0 - 64;
    float4 b0 = *(const float4*)&bl[jj];
    float4 b1 = *(const float4*)&bl[jj + 4];
#pragma unroll
    for (int r = 0; r < 4; ++r) {
      int nn = n0 + r0 + r;
      if (nn < n) {
        *(float4*)&R[(size_t)nn * 64 + jj] =
            make_float4(acc[r][0] + b0.x, acc[r][1] + b0.y, acc[r][2] + b0.z, acc[r][3] + b0.w);
        *(float4*)&R[(size_t)nn * 64 + jj + 4] =
            make_float4(acc[r][4] + b1.x, acc[r][5] + b1.y, acc[r][6] + b1.z, acc[r][7] + b1.w);
      }
    }
  }
}

// ---- fused gather + activation. One wave per node, lane j = output dim j.
// P is bf16 (random-access working set 12.8MB). R f32.
// MODE 0: relu; MODE 1: relu + residual; MODE 2: plain + L2-normalize.
template <int MODE>
__global__ __launch_bounds__(256) void k_gather(
    const unsigned short* __restrict__ Pb, const float* __restrict__ R,
    const float* __restrict__ hres, const int* __restrict__ csr,
    const int* __restrict__ rs, const float* __restrict__ invdeg,
    float* __restrict__ hout, int n) {
  int j = threadIdx.x & 63;
  int v = (blockIdx.x << 2) + (threadIdx.x >> 6);
  if (v >= n) return;
  int beg = rs[v], end = rs[v + 1];
  float a = 0.f;
  int i = beg;
  for (; i + 1 < end; i += 2) {
    int s0 = csr[i], s1 = csr[i + 1];
    unsigned short p0 = Pb[(size_t)s0 * 64 + j];
    unsigned short p1 = Pb[(size_t)s1 * 64 + j];
    a += __uint_as_float((unsigned)p0 << 16) + __uint_as_float((unsigned)p1 << 16);
  }
  if (i < end) a += __uint_as_float((unsigned)Pb[(size_t)csr[i] * 64 + j] << 16);
  float o = a * invdeg[v] + R[(size_t)v * 64 + j];
  if (MODE == 0) {
    o = fmaxf(o, 0.f);
  } else if (MODE == 1) {
    o = fmaxf(o, 0.f) + hres[(size_t)v * 64 + j];
  } else {
    float sq = o * o;
#pragma unroll
    for (int m = 1; m < 64; m <<= 1) sq += __shfl_xor(sq, m, 64);
    float nrm = fmaxf(sqrtf(sq), 1e-12f);
    o /= nrm;
  }
  hout[(size_t)v * 64 + j] = o;
}

extern "C" void kernel_launch(void* const* d_in, const int* in_sizes, int n_in,
                              void* d_out, int out_size, void* d_ws, size_t ws_size,
                              hipStream_t stream) {
  const float* x = (const float*)d_in[0];
  const unsigned int* eraw = (const unsigned int*)d_in[1];
  const float* Wl[4] = {(const float*)d_in[2], (const float*)d_in[5],
                        (const float*)d_in[8], (const float*)d_in[11]};
  const float* blv[4] = {(const float*)d_in[3], (const float*)d_in[6],
                         (const float*)d_in[9], (const float*)d_in[12]};
  const float* Wr[4] = {(const float*)d_in[4], (const float*)d_in[7],
                        (const float*)d_in[10], (const float*)d_in[13]};
  const int N = in_sizes[0] / 64;
  const int E = in_sizes[1] / 2;
  const int span = (N + 255) / 256;  // nodes per bucket; must be <= 512
  float* out = (float*)d_out;

  char* w = (char*)d_ws;
  size_t off = 0;
  int* flag = (int*)(w + off);        off = al256(off + 4);
  int* bucketCount = (int*)(w + off); off = al256(off + 256 * 4);
  int* boff = (int*)(w + off);        off = al256(off + 257 * 4);
  int* cursorB = (int*)(w + off);     off = al256(off + 256 * 4);
  int* csr = (int*)(w + off);         off = al256(off + (size_t)E * 4);
  float* invdeg = (float*)(w + off);  off = al256(off + (size_t)N * 4);
  int* rs = (int*)(w + off);          off = al256(off + (size_t)(N + 1) * 4);
  uint2* bdata = (uint2*)(w + off);   off = al256(off + (size_t)E * 8);
  float* hA = (float*)(w + off);      off = al256(off + (size_t)N * 64 * 4);
  unsigned short* Pb = (unsigned short*)(w + off); off = al256(off + (size_t)N * 64 * 2);
  float* R = (float*)(w + off);       off = al256(off + (size_t)N * 64 * 4);

  hipMemsetAsync(flag, 0, 4, stream);
  hipMemsetAsync(bucketCount, 0, 256 * 4, stream);

  int eb = (E + EPB - 1) / EPB;
  k_detect<<<1, 256, 0, stream>>>(eraw, E, flag);
  k_bcount<<<eb, 256, 0, stream>>>(eraw, E, span, flag, bucketCount);
  k_bscan<<<1, 256, 0, stream>>>(bucketCount, boff, cursorB, rs, N, E);
  k_bscatter<<<eb, 256, 0, stream>>>(eraw, E, span, flag, cursorB, bdata);
  k_bbuild<<<256, 256, 0, stream>>>(bdata, boff, span, N, csr, rs, invdeg);

  int gb = (N + 63) / 64;
  int nb4 = (N + 3) / 4;
  // Layer 1: x -> hA (relu)
  k_gemm<<<gb, 256, 0, stream>>>(x, Wl[0], Wr[0], blv[0], Pb, R, N);
  k_gather<0><<<nb4, 256, 0, stream>>>(Pb, R, nullptr, csr, rs, invdeg, hA, N);
  // Layer 2: hA -> out (relu + residual hA)
  k_gemm<<<gb, 256, 0, stream>>>(hA, Wl[1], Wr[1], blv[1], Pb, R, N);
  k_gather<1><<<nb4, 256, 0, stream>>>(Pb, R, hA, csr, rs, invdeg, out, N);
  // Layer 3: out -> hA (relu + residual out)
  k_gemm<<<gb, 256, 0, stream>>>(out, Wl[2], Wr[2], blv[2], Pb, R, N);
  k_gather<1><<<nb4, 256, 0, stream>>>(Pb, R, out, csr, rs, invdeg, hA, N);
  // Layer 4: hA -> out (no act, L2-normalize rows)
  k_gemm<<<gb, 256, 0, stream>>>(hA, Wl[3], Wr[3], blv[3], Pb, R, N);
  k_gather<2><<<nb4, 256, 0, stream>>>(Pb, R, nullptr, csr, rs, invdeg, out, N);
}

// Round 5
// 571.763 us; speedup vs baseline: 1.7871x; 1.0280x over previous
//
#include <hip/hip_runtime.h>

// GraphSAGE 4-layer encoder, N=100000 nodes, d=64, E=1.6M edges.
//   1. CSR build via 2-level bucket sort: bucket = dst/span (256 buckets),
//      LDS histograms + per-(block,bucket) reservations -> no per-node global
//      atomics, no scattered-write line thrash.
//   2. Per layer: GEMM pass P = h@Wl (stored bf16), R = h@Wr + bl (f32)
//      (linearity of mean: mean(h[src])@Wl == mean(P[src])), then fused
//      gather: h_out = act(invdeg * sum P[nbr] + R) [+residual] [L2-norm].
// R4->R5: gather was latency-bound (csr->P pointer chase, 2 edges in flight,
// ~800cy/iter). Now 16-deep batches: 1 coalesced index load + 16 shfl
// broadcasts + 16 independent P-gathers in flight; single masked tail stage.

#include <hip/hip_bf16.h>

static inline size_t al256(size_t x) { return (x + 255) & ~(size_t)255; }

#define EPB 8192  // edges per block in bucket passes

__device__ inline unsigned short f2bf(float f) {
  unsigned u = __float_as_uint(f);
  return (unsigned short)((u + 0x7fffu + ((u >> 16) & 1u)) >> 16);  // RNE
}

// ---- edge dtype detection: int64 little-endian values < 2^31 have all odd
// 32-bit words zero. flag=1 -> int32, flag=0 -> int64.
__global__ void k_detect(const unsigned int* __restrict__ raw, int E, int* __restrict__ flag) {
  int nz = 0;
#pragma unroll
  for (int k = 0; k < 64; ++k) {
    int i = threadIdx.x + (k << 8);
    if (i < E && raw[2 * (size_t)i + 1] != 0u) nz = 1;
  }
  unsigned long long b = __ballot(nz != 0);
  if ((threadIdx.x & 63) == 0 && b) atomicOr(flag, 1);
}

// ---- pass A: bucket counts via LDS histogram.
__global__ __launch_bounds__(256) void k_bcount(const unsigned int* __restrict__ raw, int E,
                                                int span, const int* __restrict__ flag,
                                                int* __restrict__ bucketCount) {
  __shared__ int lh[256];
  int t = threadIdx.x;
  lh[t] = 0;
  __syncthreads();
  int f = *flag;
  int base = blockIdx.x * EPB;
#pragma unroll 4
  for (int k = 0; k < EPB / 256; ++k) {
    int i = base + k * 256 + t;
    if (i < E) {
      int dst = f ? (int)raw[E + i] : (int)raw[2 * (size_t)(E + i)];
      atomicAdd(&lh[dst / span], 1);
    }
  }
  __syncthreads();
  int c = lh[t];
  if (c) atomicAdd(&bucketCount[t], c);
}

// ---- scan 256 bucket counts -> boff[257], init cursorB, rs[N]=E.
__global__ void k_bscan(const int* __restrict__ bucketCount, int* __restrict__ boff,
                        int* __restrict__ cursorB, int* __restrict__ rs, int N, int E) {
  __shared__ int sa[256], sb[256];
  int t = threadIdx.x;
  int v = bucketCount[t];
  sa[t] = v;
  __syncthreads();
  int* s = sa;
  int* d = sb;
  for (int off = 1; off < 256; off <<= 1) {
    d[t] = s[t] + (t >= off ? s[t - off] : 0);
    __syncthreads();
    int* tmp = s; s = d; d = tmp;
  }
  int inc = s[t];
  int ex = inc - v;
  boff[t] = ex;
  cursorB[t] = ex;
  if (t == 255) boff[256] = inc;
  if (t == 0) rs[N] = E;
}

// ---- pass B: scatter (src,dst) pairs into bucket-contiguous bdata.
__global__ __launch_bounds__(256) void k_bscatter(const unsigned int* __restrict__ raw, int E,
                                                  int span, const int* __restrict__ flag,
                                                  int* __restrict__ cursorB,
                                                  uint2* __restrict__ bdata) {
  __shared__ int lh[256], lcur[256], gbase[256];
  int t = threadIdx.x;
  lh[t] = 0;
  lcur[t] = 0;
  __syncthreads();
  int f = *flag;
  int base = blockIdx.x * EPB;
#pragma unroll 4
  for (int k = 0; k < EPB / 256; ++k) {
    int i = base + k * 256 + t;
    if (i < E) {
      int dst = f ? (int)raw[E + i] : (int)raw[2 * (size_t)(E + i)];
      atomicAdd(&lh[dst / span], 1);
    }
  }
  __syncthreads();
  int c = lh[t];
  gbase[t] = c ? atomicAdd(&cursorB[t], c) : 0;
  __syncthreads();
#pragma unroll 4
  for (int k = 0; k < EPB / 256; ++k) {
    int i = base + k * 256 + t;
    if (i < E) {
      int s_, d_;
      if (f) { s_ = (int)raw[i]; d_ = (int)raw[E + i]; }
      else   { s_ = (int)raw[2 * (size_t)i]; d_ = (int)raw[2 * (size_t)(E + i)]; }
      int b = d_ / span;
      int pos = atomicAdd(&lcur[b], 1);
      bdata[(size_t)gbase[b] + pos] = make_uint2((unsigned)s_, (unsigned)d_);
    }
  }
}

// ---- pass C: one block per bucket. Node histogram + scan in LDS, write
// rs/invdeg, scatter src ids into the bucket's contiguous csr window.
// Requires span <= 512 (N <= 131072).
__global__ __launch_bounds__(256) void k_bbuild(const uint2* __restrict__ bdata,
                                                const int* __restrict__ boff, int span, int N,
                                                int* __restrict__ csr, int* __restrict__ rs,
                                                float* __restrict__ invdeg) {
  __shared__ int cnt[512], sa[512], sb[512], cur[512];
  int b = blockIdx.x;
  int t = threadIdx.x;
  int node0 = b * span;
  int beg = boff[b], end = boff[b + 1];
  cnt[t] = 0;
  cnt[t + 256] = 0;
  __syncthreads();
  for (int i = beg + t; i < end; i += 256) {
    int d = (int)bdata[i].y - node0;
    atomicAdd(&cnt[d], 1);
  }
  __syncthreads();
  sa[t] = cnt[t];
  sa[t + 256] = cnt[t + 256];
  __syncthreads();
  int* s = sa;
  int* d = sb;
  for (int off = 1; off < 512; off <<= 1) {
    d[t] = s[t] + (t >= off ? s[t - off] : 0);
    int i2 = t + 256;
    d[i2] = s[i2] + (i2 >= off ? s[i2 - off] : 0);
    __syncthreads();
    int* tmp = s; s = d; d = tmp;
  }
  int ex0 = s[t] - cnt[t];
  int ex1 = s[t + 256] - cnt[t + 256];
  cur[t] = ex0;
  cur[t + 256] = ex1;
  if (t < span) {
    int node = node0 + t;
    if (node < N) {
      rs[node] = beg + ex0;
      invdeg[node] = 1.0f / fmaxf((float)cnt[t], 1.0f);
    }
  }
  int t2 = t + 256;
  if (t2 < span) {
    int node = node0 + t2;
    if (node < N) {
      rs[node] = beg + ex1;
      invdeg[node] = 1.0f / fmaxf((float)cnt[t2], 1.0f);
    }
  }
  __syncthreads();
  for (int i = beg + t; i < end; i += 256) {
    uint2 p = bdata[i];
    int dd = (int)p.y - node0;
    int pos = atomicAdd(&cur[dd], 1);
    csr[beg + pos] = (int)p.x;
  }
}

// ---- GEMM: P(bf16) = h @ Wl ; R(f32) = h @ Wr + bl. Tile 64 nodes x 128 cols.
__global__ __launch_bounds__(256) void k_gemm(
    const float* __restrict__ h, const float* __restrict__ Wl,
    const float* __restrict__ Wr, const float* __restrict__ bl,
    unsigned short* __restrict__ Pb, float* __restrict__ R, int n) {
  __shared__ float hT[64][68];   // transposed h tile, padded
  __shared__ float W2[64][128];  // [k][j]: j<64 -> Wl, else Wr
  int t = threadIdx.x;
  int n0 = blockIdx.x * 64;

  for (int idx = t; idx < 64 * 128; idx += 256) {
    int k = idx >> 7, j = idx & 127;
    W2[k][j] = (j < 64) ? Wl[k * 64 + j] : Wr[k * 64 + (j - 64)];
  }
  for (int idx = t; idx < 64 * 16; idx += 256) {
    int r = idx >> 4;
    int k4 = (idx & 15) * 4;
    int nn = n0 + r;
    float4 hv = (nn < n) ? *(const float4*)&h[(size_t)nn * 64 + k4]
                         : make_float4(0.f, 0.f, 0.f, 0.f);
    hT[k4 + 0][r] = hv.x;
    hT[k4 + 1][r] = hv.y;
    hT[k4 + 2][r] = hv.z;
    hT[k4 + 3][r] = hv.w;
  }
  __syncthreads();

  int j0 = (t & 15) * 8;
  int r0 = (t >> 4) * 4;
  float acc[4][8] = {};
#pragma unroll 8
  for (int k = 0; k < 64; ++k) {
    float4 hv = *(const float4*)&hT[k][r0];
    float wv[8];
    *(float4*)&wv[0] = *(const float4*)&W2[k][j0];
    *(float4*)&wv[4] = *(const float4*)&W2[k][j0 + 4];
    float hr[4] = {hv.x, hv.y, hv.z, hv.w};
#pragma unroll
    for (int r = 0; r < 4; ++r)
#pragma unroll
      for (int c = 0; c < 8; ++c) acc[r][c] = fmaf(hr[r], wv[c], acc[r][c]);
  }

  if (j0 < 64) {
#pragma unroll
    for (int r = 0; r < 4; ++r) {
      int nn = n0 + r0 + r;
      if (nn < n) {
        union { unsigned short us[8]; uint4 u4; } pk;
#pragma unroll
        for (int c = 0; c < 8; ++c) pk.us[c] = f2bf(acc[r][c]);
        *(uint4*)&Pb[(size_t)nn * 64 + j0] = pk.u4;
      }
    }
  } else {
    int jj = j0 - 64;
    float4 b0 = *(const float4*)&bl[jj];
    float4 b1 = *(const float4*)&bl[jj + 4];
#pragma unroll
    for (int r = 0; r < 4; ++r) {
      int nn = n0 + r0 + r;
      if (nn < n) {
        *(float4*)&R[(size_t)nn * 64 + jj] =
            make_float4(acc[r][0] + b0.x, acc[r][1] + b0.y, acc[r][2] + b0.z, acc[r][3] + b0.w);
        *(float4*)&R[(size_t)nn * 64 + jj + 4] =
            make_float4(acc[r][4] + b1.x, acc[r][5] + b1.y, acc[r][6] + b1.z, acc[r][7] + b1.w);
      }
    }
  }
}

// ---- fused gather + activation. One wave per node, lane j = output dim j.
// 16-deep MLP batches: one coalesced csr load -> 16 shfl-broadcast indices ->
// 16 independent bf16 row-gathers in flight. Single masked tail stage.
// MODE 0: relu; MODE 1: relu + residual; MODE 2: plain + L2-normalize.
template <int MODE>
__global__ __launch_bounds__(256) void k_gather(
    const unsigned short* __restrict__ Pb, const float* __restrict__ R,
    const float* __restrict__ hres, const int* __restrict__ csr,
    const int* __restrict__ rs, const float* __restrict__ invdeg,
    float* __restrict__ hout, int n) {
  int j = threadIdx.x & 63;
  int v = (blockIdx.x << 2) + (threadIdx.x >> 6);
  if (v >= n) return;
  int beg = rs[v], end = rs[v + 1];
  float a = 0.f;
  int i = beg;

  // main: full 16-edge batches
  for (; i + 16 <= end; i += 16) {
    int myidx = csr[i + (j & 15)];  // one 64B transaction, 4x broadcast
    int s[16];
#pragma unroll
    for (int k = 0; k < 16; ++k) s[k] = __shfl(myidx, k, 64);
    unsigned short pv[16];
#pragma unroll
    for (int k = 0; k < 16; ++k) pv[k] = Pb[((size_t)s[k] << 6) + j];
#pragma unroll
    for (int k = 0; k < 16; ++k) a += __uint_as_float((unsigned)pv[k] << 16);
  }
  // tail: one masked stage, r in [1,15]; branch is wave-uniform
  int r = end - i;
  if (r > 0) {
    int off = j & 15;
    if (off >= r) off = r - 1;
    int myidx = csr[i + off];
    int s[16];
#pragma unroll
    for (int k = 0; k < 16; ++k) s[k] = __shfl(myidx, k, 64);
    unsigned short pv[16];
#pragma unroll
    for (int k = 0; k < 16; ++k)
      if (k < r) pv[k] = Pb[((size_t)s[k] << 6) + j];
#pragma unroll
    for (int k = 0; k < 16; ++k)
      if (k < r) a += __uint_as_float((unsigned)pv[k] << 16);
  }

  float o = a * invdeg[v] + R[(size_t)v * 64 + j];
  if (MODE == 0) {
    o = fmaxf(o, 0.f);
  } else if (MODE == 1) {
    o = fmaxf(o, 0.f) + hres[(size_t)v * 64 + j];
  } else {
    float sq = o * o;
#pragma unroll
    for (int m = 1; m < 64; m <<= 1) sq += __shfl_xor(sq, m, 64);
    float nrm = fmaxf(sqrtf(sq), 1e-12f);
    o /= nrm;
  }
  hout[(size_t)v * 64 + j] = o;
}

extern "C" void kernel_launch(void* const* d_in, const int* in_sizes, int n_in,
                              void* d_out, int out_size, void* d_ws, size_t ws_size,
                              hipStream_t stream) {
  const float* x = (const float*)d_in[0];
  const unsigned int* eraw = (const unsigned int*)d_in[1];
  const float* Wl[4] = {(const float*)d_in[2], (const float*)d_in[5],
                        (const float*)d_in[8], (const float*)d_in[11]};
  const float* blv[4] = {(const float*)d_in[3], (const float*)d_in[6],
                         (const float*)d_in[9], (const float*)d_in[12]};
  const float* Wr[4] = {(const float*)d_in[4], (const float*)d_in[7],
                        (const float*)d_in[10], (const float*)d_in[13]};
  const int N = in_sizes[0] / 64;
  const int E = in_sizes[1] / 2;
  const int span = (N + 255) / 256;  // nodes per bucket; must be <= 512
  float* out = (float*)d_out;

  char* w = (char*)d_ws;
  size_t off = 0;
  int* flag = (int*)(w + off);        off = al256(off + 4);
  int* bucketCount = (int*)(w + off); off = al256(off + 256 * 4);
  int* boff = (int*)(w + off);        off = al256(off + 257 * 4);
  int* cursorB = (int*)(w + off);     off = al256(off + 256 * 4);
  int* csr = (int*)(w + off);         off = al256(off + (size_t)E * 4);
  float* invdeg = (float*)(w + off);  off = al256(off + (size_t)N * 4);
  int* rs = (int*)(w + off);          off = al256(off + (size_t)(N + 1) * 4);
  uint2* bdata = (uint2*)(w + off);   off = al256(off + (size_t)E * 8);
  float* hA = (float*)(w + off);      off = al256(off + (size_t)N * 64 * 4);
  unsigned short* Pb = (unsigned short*)(w + off); off = al256(off + (size_t)N * 64 * 2);
  float* R = (float*)(w + off);       off = al256(off + (size_t)N * 64 * 4);

  hipMemsetAsync(flag, 0, 4, stream);
  hipMemsetAsync(bucketCount, 0, 256 * 4, stream);

  int eb = (E + EPB - 1) / EPB;
  k_detect<<<1, 256, 0, stream>>>(eraw, E, flag);
  k_bcount<<<eb, 256, 0, stream>>>(eraw, E, span, flag, bucketCount);
  k_bscan<<<1, 256, 0, stream>>>(bucketCount, boff, cursorB, rs, N, E);
  k_bscatter<<<eb, 256, 0, stream>>>(eraw, E, span, flag, cursorB, bdata);
  k_bbuild<<<256, 256, 0, stream>>>(bdata, boff, span, N, csr, rs, invdeg);

  int gb = (N + 63) / 64;
  int nb4 = (N + 3) / 4;
  // Layer 1: x -> hA (relu)
  k_gemm<<<gb, 256, 0, stream>>>(x, Wl[0], Wr[0], blv[0], Pb, R, N);
  k_gather<0><<<nb4, 256, 0, stream>>>(Pb, R, nullptr, csr, rs, invdeg, hA, N);
  // Layer 2: hA -> out (relu + residual hA)
  k_gemm<<<gb, 256, 0, stream>>>(hA, Wl[1], Wr[1], blv[1], Pb, R, N);
  k_gather<1><<<nb4, 256, 0, stream>>>(Pb, R, hA, csr, rs, invdeg, out, N);
  // Layer 3: out -> hA (relu + residual out)
  k_gemm<<<gb, 256, 0, stream>>>(out, Wl[2], Wr[2], blv[2], Pb, R, N);
  k_gather<1><<<nb4, 256, 0, stream>>>(Pb, R, out, csr, rs, invdeg, hA, N);
  // Layer 4: hA -> out (no act, L2-normalize rows)
  k_gemm<<<gb, 256, 0, stream>>>(hA, Wl[3], Wr[3], blv[3], Pb, R, N);
  k_gather<2><<<nb4, 256, 0, stream>>>(Pb, R, nullptr, csr, rs, invdeg, out, N);
}

// Round 6
// 411.357 us; speedup vs baseline: 2.4840x; 1.3899x over previous
//
#include <hip/hip_runtime.h>

// GraphSAGE 4-layer encoder, N=100000 nodes, d=64, E=1.6M edges.
//   1. CSR build via 2-level bucket sort (no per-node global atomics).
//   2. Per layer: GEMM P = h@Wl (bf16), R = h@Wr + bl (f32); fused gather:
//      h_out = act(invdeg * sum P[nbr] + R) [+residual] [L2-norm].
// R5->R6: gather was instruction-bound (~8 instr/edge, invariant across
// f32/bf16/serial/MLP variants, VALUBusy~42%). Now 2 edges per dword load
// (lane halves cover 2 rows), 32-bit saddr addressing, float2 accumulate,
// one shfl_xor(32) to combine halves: ~3 instr/edge.

#include <hip/hip_bf16.h>

static inline size_t al256(size_t x) { return (x + 255) & ~(size_t)255; }

#define EPB 8192  // edges per block in bucket passes

__device__ inline unsigned short f2bf(float f) {
  unsigned u = __float_as_uint(f);
  return (unsigned short)((u + 0x7fffu + ((u >> 16) & 1u)) >> 16);  // RNE
}

// ---- edge dtype detection: int64 little-endian values < 2^31 have all odd
// 32-bit words zero. flag=1 -> int32, flag=0 -> int64.
__global__ void k_detect(const unsigned int* __restrict__ raw, int E, int* __restrict__ flag) {
  int nz = 0;
#pragma unroll
  for (int k = 0; k < 64; ++k) {
    int i = threadIdx.x + (k << 8);
    if (i < E && raw[2 * (size_t)i + 1] != 0u) nz = 1;
  }
  unsigned long long b = __ballot(nz != 0);
  if ((threadIdx.x & 63) == 0 && b) atomicOr(flag, 1);
}

// ---- pass A: bucket counts via LDS histogram.
__global__ __launch_bounds__(256) void k_bcount(const unsigned int* __restrict__ raw, int E,
                                                int span, const int* __restrict__ flag,
                                                int* __restrict__ bucketCount) {
  __shared__ int lh[256];
  int t = threadIdx.x;
  lh[t] = 0;
  __syncthreads();
  int f = *flag;
  int base = blockIdx.x * EPB;
#pragma unroll 4
  for (int k = 0; k < EPB / 256; ++k) {
    int i = base + k * 256 + t;
    if (i < E) {
      int dst = f ? (int)raw[E + i] : (int)raw[2 * (size_t)(E + i)];
      atomicAdd(&lh[dst / span], 1);
    }
  }
  __syncthreads();
  int c = lh[t];
  if (c) atomicAdd(&bucketCount[t], c);
}

// ---- scan 256 bucket counts -> boff[257], init cursorB, rs[N]=E.
__global__ void k_bscan(const int* __restrict__ bucketCount, int* __restrict__ boff,
                        int* __restrict__ cursorB, int* __restrict__ rs, int N, int E) {
  __shared__ int sa[256], sb[256];
  int t = threadIdx.x;
  int v = bucketCount[t];
  sa[t] = v;
  __syncthreads();
  int* s = sa;
  int* d = sb;
  for (int off = 1; off < 256; off <<= 1) {
    d[t] = s[t] + (t >= off ? s[t - off] : 0);
    __syncthreads();
    int* tmp = s; s = d; d = tmp;
  }
  int inc = s[t];
  int ex = inc - v;
  boff[t] = ex;
  cursorB[t] = ex;
  if (t == 255) boff[256] = inc;
  if (t == 0) rs[N] = E;
}

// ---- pass B: scatter (src,dst) pairs into bucket-contiguous bdata.
__global__ __launch_bounds__(256) void k_bscatter(const unsigned int* __restrict__ raw, int E,
                                                  int span, const int* __restrict__ flag,
                                                  int* __restrict__ cursorB,
                                                  uint2* __restrict__ bdata) {
  __shared__ int lh[256], lcur[256], gbase[256];
  int t = threadIdx.x;
  lh[t] = 0;
  lcur[t] = 0;
  __syncthreads();
  int f = *flag;
  int base = blockIdx.x * EPB;
#pragma unroll 4
  for (int k = 0; k < EPB / 256; ++k) {
    int i = base + k * 256 + t;
    if (i < E) {
      int dst = f ? (int)raw[E + i] : (int)raw[2 * (size_t)(E + i)];
      atomicAdd(&lh[dst / span], 1);
    }
  }
  __syncthreads();
  int c = lh[t];
  gbase[t] = c ? atomicAdd(&cursorB[t], c) : 0;
  __syncthreads();
#pragma unroll 4
  for (int k = 0; k < EPB / 256; ++k) {
    int i = base + k * 256 + t;
    if (i < E) {
      int s_, d_;
      if (f) { s_ = (int)raw[i]; d_ = (int)raw[E + i]; }
      else   { s_ = (int)raw[2 * (size_t)i]; d_ = (int)raw[2 * (size_t)(E + i)]; }
      int b = d_ / span;
      int pos = atomicAdd(&lcur[b], 1);
      bdata[(size_t)gbase[b] + pos] = make_uint2((unsigned)s_, (unsigned)d_);
    }
  }
}

// ---- pass C: one block per bucket. Node histogram + scan in LDS, write
// rs/invdeg, scatter src ids into the bucket's contiguous csr window.
// Requires span <= 512 (N <= 131072).
__global__ __launch_bounds__(256) void k_bbuild(const uint2* __restrict__ bdata,
                                                const int* __restrict__ boff, int span, int N,
                                                int* __restrict__ csr, int* __restrict__ rs,
                                                float* __restrict__ invdeg) {
  __shared__ int cnt[512], sa[512], sb[512], cur[512];
  int b = blockIdx.x;
  int t = threadIdx.x;
  int node0 = b * span;
  int beg = boff[b], end = boff[b + 1];
  cnt[t] = 0;
  cnt[t + 256] = 0;
  __syncthreads();
  for (int i = beg + t; i < end; i += 256) {
    int d = (int)bdata[i].y - node0;
    atomicAdd(&cnt[d], 1);
  }
  __syncthreads();
  sa[t] = cnt[t];
  sa[t + 256] = cnt[t + 256];
  __syncthreads();
  int* s = sa;
  int* d = sb;
  for (int off = 1; off < 512; off <<= 1) {
    d[t] = s[t] + (t >= off ? s[t - off] : 0);
    int i2 = t + 256;
    d[i2] = s[i2] + (i2 >= off ? s[i2 - off] : 0);
    __syncthreads();
    int* tmp = s; s = d; d = tmp;
  }
  int ex0 = s[t] - cnt[t];
  int ex1 = s[t + 256] - cnt[t + 256];
  cur[t] = ex0;
  cur[t + 256] = ex1;
  if (t < span) {
    int node = node0 + t;
    if (node < N) {
      rs[node] = beg + ex0;
      invdeg[node] = 1.0f / fmaxf((float)cnt[t], 1.0f);
    }
  }
  int t2 = t + 256;
  if (t2 < span) {
    int node = node0 + t2;
    if (node < N) {
      rs[node] = beg + ex1;
      invdeg[node] = 1.0f / fmaxf((float)cnt[t2], 1.0f);
    }
  }
  __syncthreads();
  for (int i = beg + t; i < end; i += 256) {
    uint2 p = bdata[i];
    int dd = (int)p.y - node0;
    int pos = atomicAdd(&cur[dd], 1);
    csr[beg + pos] = (int)p.x;
  }
}

// ---- GEMM: P(bf16) = h @ Wl ; R(f32) = h @ Wr + bl. Tile 64 nodes x 128 cols.
__global__ __launch_bounds__(256) void k_gemm(
    const float* __restrict__ h, const float* __restrict__ Wl,
    const float* __restrict__ Wr, const float* __restrict__ bl,
    unsigned short* __restrict__ Pb, float* __restrict__ R, int n) {
  __shared__ float hT[64][68];   // transposed h tile, padded
  __shared__ float W2[64][128];  // [k][j]: j<64 -> Wl, else Wr
  int t = threadIdx.x;
  int n0 = blockIdx.x * 64;

  for (int idx = t; idx < 64 * 128; idx += 256) {
    int k = idx >> 7, j = idx & 127;
    W2[k][j] = (j < 64) ? Wl[k * 64 + j] : Wr[k * 64 + (j - 64)];
  }
  for (int idx = t; idx < 64 * 16; idx += 256) {
    int r = idx >> 4;
    int k4 = (idx & 15) * 4;
    int nn = n0 + r;
    float4 hv = (nn < n) ? *(const float4*)&h[(size_t)nn * 64 + k4]
                         : make_float4(0.f, 0.f, 0.f, 0.f);
    hT[k4 + 0][r] = hv.x;
    hT[k4 + 1][r] = hv.y;
    hT[k4 + 2][r] = hv.z;
    hT[k4 + 3][r] = hv.w;
  }
  __syncthreads();

  int j0 = (t & 15) * 8;
  int r0 = (t >> 4) * 4;
  float acc[4][8] = {};
#pragma unroll 8
  for (int k = 0; k < 64; ++k) {
    float4 hv = *(const float4*)&hT[k][r0];
    float wv[8];
    *(float4*)&wv[0] = *(const float4*)&W2[k][j0];
    *(float4*)&wv[4] = *(const float4*)&W2[k][j0 + 4];
    float hr[4] = {hv.x, hv.y, hv.z, hv.w};
#pragma unroll
    for (int r = 0; r < 4; ++r)
#pragma unroll
      for (int c = 0; c < 8; ++c) acc[r][c] = fmaf(hr[r], wv[c], acc[r][c]);
  }

  if (j0 < 64) {
#pragma unroll
    for (int r = 0; r < 4; ++r) {
      int nn = n0 + r0 + r;
      if (nn < n) {
        union { unsigned short us[8]; uint4 u4; } pk;
#pragma unroll
        for (int c = 0; c < 8; ++c) pk.us[c] = f2bf(acc[r][c]);
        *(uint4*)&Pb[(size_t)nn * 64 + j0] = pk.u4;
      }
    }
  } else {
    int jj = j0 - 64;
    float4 b0 = *(const float4*)&bl[jj];
    float4 b1 = *(const float4*)&bl[jj + 4];
#pragma unroll
    for (int r = 0; r < 4; ++r) {
      int nn = n0 + r0 + r;
      if (nn < n) {
        *(float4*)&R[(size_t)nn * 64 + jj] =
            make_float4(acc[r][0] + b0.x, acc[r][1] + b0.y, acc[r][2] + b0.z, acc[r][3] + b0.w);
        *(float4*)&R[(size_t)nn * 64 + jj + 4] =
            make_float4(acc[r][4] + b1.x, acc[r][5] + b1.y, acc[r][6] + b1.z, acc[r][7] + b1.w);
      }
    }
  }
}

// ---- fused gather + activation. One wave per node; lane halves process 2
// rows per dword load (lane l<32: row csr[i+2t] dims (2q,2q+1); l>=32: row
// csr[i+2t+1]). 32-bit saddr indexing into Pb as uint array. Halves combined
// with one shfl_xor(32). MODE 0 relu; 1 relu+residual; 2 plain+L2-normalize.
template <int MODE>
__global__ __launch_bounds__(256) void k_gather(
    const unsigned short* __restrict__ Pb, const float* __restrict__ R,
    const float* __restrict__ hres, const int* __restrict__ csr,
    const int* __restrict__ rs, const float* __restrict__ invdeg,
    float* __restrict__ hout, int n) {
  const unsigned* __restrict__ Pb32 = (const unsigned*)Pb;
  int l = threadIdx.x & 63;
  int v = (blockIdx.x << 2) + (threadIdx.x >> 6);
  if (v >= n) return;
  int h = l >> 5;   // which row of the pair this lane covers
  int q = l & 31;   // dim-pair index (dims 2q, 2q+1)
  int beg = rs[v], end = rs[v + 1];
  float idg = invdeg[v];
  // independent early loads (off the csr->P dependency chain)
  float2 rv = *(const float2*)&R[((size_t)v << 6) + (q << 1)];
  float2 hv = make_float2(0.f, 0.f);
  if (MODE == 1) hv = *(const float2*)&hres[((size_t)v << 6) + (q << 1)];

  float2 a = make_float2(0.f, 0.f);
  int i = beg;
  int h4 = h << 2;  // byte offset of this lane's half in the bpermute
  for (; i + 16 <= end; i += 16) {
    int myidx = csr[i + (l & 15)];  // one 64B line, broadcast 4x
#pragma unroll
    for (int t = 0; t < 8; ++t) {
      int sel = __shfl(myidx, 2 * t + h, 64);
      unsigned u = Pb32[(unsigned)((sel << 5) + q)];
      a.x += __uint_as_float(u << 16);
      a.y += __uint_as_float(u & 0xffff0000u);
    }
  }
  int r = end - i;
  if (r > 0) {  // masked tail, r in [1,15], wave-uniform branch
    int cl = r - 1;
    int lo = l & 15;
    int myidx = csr[i + (lo <= cl ? lo : cl)];
#pragma unroll
    for (int t = 0; t < 8; ++t) {
      if (2 * t >= r) break;  // wave-uniform
      int e = 2 * t + h;
      int sel = __shfl(myidx, e <= cl ? e : cl, 64);
      unsigned u = Pb32[(unsigned)((sel << 5) + q)];
      float m = (e < r) ? 1.f : 0.f;
      a.x = fmaf(m, __uint_as_float(u << 16), a.x);
      a.y = fmaf(m, __uint_as_float(u & 0xffff0000u), a.y);
    }
  }
  (void)h4;
  // combine the two lane-half partial sums
  a.x += __shfl_xor(a.x, 32, 64);
  a.y += __shfl_xor(a.y, 32, 64);

  if (l < 32) {
    float2 o;
    o.x = a.x * idg + rv.x;
    o.y = a.y * idg + rv.y;
    if (MODE == 0) {
      o.x = fmaxf(o.x, 0.f);
      o.y = fmaxf(o.y, 0.f);
    } else if (MODE == 1) {
      o.x = fmaxf(o.x, 0.f) + hv.x;
      o.y = fmaxf(o.y, 0.f) + hv.y;
    } else {
      float sq = o.x * o.x + o.y * o.y;
#pragma unroll
      for (int m = 1; m < 32; m <<= 1) sq += __shfl_xor(sq, m, 64);
      float nrm = fmaxf(sqrtf(sq), 1e-12f);
      o.x /= nrm;
      o.y /= nrm;
    }
    *(float2*)&hout[((size_t)v << 6) + (q << 1)] = o;
  }
}

extern "C" void kernel_launch(void* const* d_in, const int* in_sizes, int n_in,
                              void* d_out, int out_size, void* d_ws, size_t ws_size,
                              hipStream_t stream) {
  const float* x = (const float*)d_in[0];
  const unsigned int* eraw = (const unsigned int*)d_in[1];
  const float* Wl[4] = {(const float*)d_in[2], (const float*)d_in[5],
                        (const float*)d_in[8], (const float*)d_in[11]};
  const float* blv[4] = {(const float*)d_in[3], (const float*)d_in[6],
                         (const float*)d_in[9], (const float*)d_in[12]};
  const float* Wr[4] = {(const float*)d_in[4], (const float*)d_in[7],
                        (const float*)d_in[10], (const float*)d_in[13]};
  const int N = in_sizes[0] / 64;
  const int E = in_sizes[1] / 2;
  const int span = (N + 255) / 256;  // nodes per bucket; must be <= 512
  float* out = (float*)d_out;

  char* w = (char*)d_ws;
  size_t off = 0;
  int* flag = (int*)(w + off);        off = al256(off + 4);
  int* bucketCount = (int*)(w + off); off = al256(off + 256 * 4);
  int* boff = (int*)(w + off);        off = al256(off + 257 * 4);
  int* cursorB = (int*)(w + off);     off = al256(off + 256 * 4);
  int* csr = (int*)(w + off);         off = al256(off + (size_t)E * 4);
  float* invdeg = (float*)(w + off);  off = al256(off + (size_t)N * 4);
  int* rs = (int*)(w + off);          off = al256(off + (size_t)(N + 1) * 4);
  uint2* bdata = (uint2*)(w + off);   off = al256(off + (size_t)E * 8);
  float* hA = (float*)(w + off);      off = al256(off + (size_t)N * 64 * 4);
  unsigned short* Pb = (unsigned short*)(w + off); off = al256(off + (size_t)N * 64 * 2);
  float* R = (float*)(w + off);       off = al256(off + (size_t)N * 64 * 4);

  hipMemsetAsync(flag, 0, 4, stream);
  hipMemsetAsync(bucketCount, 0, 256 * 4, stream);

  int eb = (E + EPB - 1) / EPB;
  k_detect<<<1, 256, 0, stream>>>(eraw, E, flag);
  k_bcount<<<eb, 256, 0, stream>>>(eraw, E, span, flag, bucketCount);
  k_bscan<<<1, 256, 0, stream>>>(bucketCount, boff, cursorB, rs, N, E);
  k_bscatter<<<eb, 256, 0, stream>>>(eraw, E, span, flag, cursorB, bdata);
  k_bbuild<<<256, 256, 0, stream>>>(bdata, boff, span, N, csr, rs, invdeg);

  int gb = (N + 63) / 64;
  int nb4 = (N + 3) / 4;
  // Layer 1: x -> hA (relu)
  k_gemm<<<gb, 256, 0, stream>>>(x, Wl[0], Wr[0], blv[0], Pb, R, N);
  k_gather<0><<<nb4, 256, 0, stream>>>(Pb, R, nullptr, csr, rs, invdeg, hA, N);
  // Layer 2: hA -> out (relu + residual hA)
  k_gemm<<<gb, 256, 0, stream>>>(hA, Wl[1], Wr[1], blv[1], Pb, R, N);
  k_gather<1><<<nb4, 256, 0, stream>>>(Pb, R, hA, csr, rs, invdeg, out, N);
  // Layer 3: out -> hA (relu + residual out)
  k_gemm<<<gb, 256, 0, stream>>>(out, Wl[2], Wr[2], blv[2], Pb, R, N);
  k_gather<1><<<nb4, 256, 0, stream>>>(Pb, R, out, csr, rs, invdeg, hA, N);
  // Layer 4: hA -> out (no act, L2-normalize rows)
  k_gemm<<<gb, 256, 0, stream>>>(hA, Wl[3], Wr[3], blv[3], Pb, R, N);
  k_gather<2><<<nb4, 256, 0, stream>>>(Pb, R, nullptr, csr, rs, invdeg, out, N);
}

// Round 7
// 386.548 us; speedup vs baseline: 2.6434x; 1.0642x over previous
//
#include <hip/hip_runtime.h>

// GraphSAGE 4-layer encoder, N=100000 nodes, d=64, E=1.6M edges.
//   1. CSR build via 2-level bucket sort (no per-node global atomics).
//   2. Per layer: GEMM P = h@Wl (f16), R = h@Wr + bl (f32); fused gather:
//      h_out = act(invdeg * sum P[nbr] + R) [+residual] [L2-norm].
// R6->R7: gather still instruction-bound (VALU 53%). P now f16: packed
// v_pk_add_f16 accumulate (1 instr / 2 dims, flushed to f32 per 16-edge
// batch), 4 rows per dwordx2 load (16 lanes x 8B per row), 4 shfl per
// batch. ~2 instr/edge vs ~3.6.

#include <hip/hip_bf16.h>

static inline size_t al256(size_t x) { return (x + 255) & ~(size_t)255; }

#define EPB 8192  // edges per block in bucket passes

// ---- edge dtype detection: int64 little-endian values < 2^31 have all odd
// 32-bit words zero. flag=1 -> int32, flag=0 -> int64.
__global__ void k_detect(const unsigned int* __restrict__ raw, int E, int* __restrict__ flag) {
  int nz = 0;
#pragma unroll
  for (int k = 0; k < 64; ++k) {
    int i = threadIdx.x + (k << 8);
    if (i < E && raw[2 * (size_t)i + 1] != 0u) nz = 1;
  }
  unsigned long long b = __ballot(nz != 0);
  if ((threadIdx.x & 63) == 0 && b) atomicOr(flag, 1);
}

// ---- pass A: bucket counts via LDS histogram.
__global__ __launch_bounds__(256) void k_bcount(const unsigned int* __restrict__ raw, int E,
                                                int span, const int* __restrict__ flag,
                                                int* __restrict__ bucketCount) {
  __shared__ int lh[256];
  int t = threadIdx.x;
  lh[t] = 0;
  __syncthreads();
  int f = *flag;
  int base = blockIdx.x * EPB;
#pragma unroll 4
  for (int k = 0; k < EPB / 256; ++k) {
    int i = base + k * 256 + t;
    if (i < E) {
      int dst = f ? (int)raw[E + i] : (int)raw[2 * (size_t)(E + i)];
      atomicAdd(&lh[dst / span], 1);
    }
  }
  __syncthreads();
  int c = lh[t];
  if (c) atomicAdd(&bucketCount[t], c);
}

// ---- scan 256 bucket counts -> boff[257], init cursorB, rs[N]=E.
__global__ void k_bscan(const int* __restrict__ bucketCount, int* __restrict__ boff,
                        int* __restrict__ cursorB, int* __restrict__ rs, int N, int E) {
  __shared__ int sa[256], sb[256];
  int t = threadIdx.x;
  int v = bucketCount[t];
  sa[t] = v;
  __syncthreads();
  int* s = sa;
  int* d = sb;
  for (int off = 1; off < 256; off <<= 1) {
    d[t] = s[t] + (t >= off ? s[t - off] : 0);
    __syncthreads();
    int* tmp = s; s = d; d = tmp;
  }
  int inc = s[t];
  int ex = inc - v;
  boff[t] = ex;
  cursorB[t] = ex;
  if (t == 255) boff[256] = inc;
  if (t == 0) rs[N] = E;
}

// ---- pass B: scatter (src,dst) pairs into bucket-contiguous bdata.
__global__ __launch_bounds__(256) void k_bscatter(const unsigned int* __restrict__ raw, int E,
                                                  int span, const int* __restrict__ flag,
                                                  int* __restrict__ cursorB,
                                                  uint2* __restrict__ bdata) {
  __shared__ int lh[256], lcur[256], gbase[256];
  int t = threadIdx.x;
  lh[t] = 0;
  lcur[t] = 0;
  __syncthreads();
  int f = *flag;
  int base = blockIdx.x * EPB;
#pragma unroll 4
  for (int k = 0; k < EPB / 256; ++k) {
    int i = base + k * 256 + t;
    if (i < E) {
      int dst = f ? (int)raw[E + i] : (int)raw[2 * (size_t)(E + i)];
      atomicAdd(&lh[dst / span], 1);
    }
  }
  __syncthreads();
  int c = lh[t];
  gbase[t] = c ? atomicAdd(&cursorB[t], c) : 0;
  __syncthreads();
#pragma unroll 4
  for (int k = 0; k < EPB / 256; ++k) {
    int i = base + k * 256 + t;
    if (i < E) {
      int s_, d_;
      if (f) { s_ = (int)raw[i]; d_ = (int)raw[E + i]; }
      else   { s_ = (int)raw[2 * (size_t)i]; d_ = (int)raw[2 * (size_t)(E + i)]; }
      int b = d_ / span;
      int pos = atomicAdd(&lcur[b], 1);
      bdata[(size_t)gbase[b] + pos] = make_uint2((unsigned)s_, (unsigned)d_);
    }
  }
}

// ---- pass C: one block per bucket. Node histogram + scan in LDS, write
// rs/invdeg, scatter src ids into the bucket's contiguous csr window.
// Requires span <= 512 (N <= 131072).
__global__ __launch_bounds__(256) void k_bbuild(const uint2* __restrict__ bdata,
                                                const int* __restrict__ boff, int span, int N,
                                                int* __restrict__ csr, int* __restrict__ rs,
                                                float* __restrict__ invdeg) {
  __shared__ int cnt[512], sa[512], sb[512], cur[512];
  int b = blockIdx.x;
  int t = threadIdx.x;
  int node0 = b * span;
  int beg = boff[b], end = boff[b + 1];
  cnt[t] = 0;
  cnt[t + 256] = 0;
  __syncthreads();
  for (int i = beg + t; i < end; i += 256) {
    int d = (int)bdata[i].y - node0;
    atomicAdd(&cnt[d], 1);
  }
  __syncthreads();
  sa[t] = cnt[t];
  sa[t + 256] = cnt[t + 256];
  __syncthreads();
  int* s = sa;
  int* d = sb;
  for (int off = 1; off < 512; off <<= 1) {
    d[t] = s[t] + (t >= off ? s[t - off] : 0);
    int i2 = t + 256;
    d[i2] = s[i2] + (i2 >= off ? s[i2 - off] : 0);
    __syncthreads();
    int* tmp = s; s = d; d = tmp;
  }
  int ex0 = s[t] - cnt[t];
  int ex1 = s[t + 256] - cnt[t + 256];
  cur[t] = ex0;
  cur[t + 256] = ex1;
  if (t < span) {
    int node = node0 + t;
    if (node < N) {
      rs[node] = beg + ex0;
      invdeg[node] = 1.0f / fmaxf((float)cnt[t], 1.0f);
    }
  }
  int t2 = t + 256;
  if (t2 < span) {
    int node = node0 + t2;
    if (node < N) {
      rs[node] = beg + ex1;
      invdeg[node] = 1.0f / fmaxf((float)cnt[t2], 1.0f);
    }
  }
  __syncthreads();
  for (int i = beg + t; i < end; i += 256) {
    uint2 p = bdata[i];
    int dd = (int)p.y - node0;
    int pos = atomicAdd(&cur[dd], 1);
    csr[beg + pos] = (int)p.x;
  }
}

// ---- GEMM: P(f16) = h @ Wl ; R(f32) = h @ Wr + bl. Tile 64 nodes x 128 cols.
__global__ __launch_bounds__(256) void k_gemm(
    const float* __restrict__ h, const float* __restrict__ Wl,
    const float* __restrict__ Wr, const float* __restrict__ bl,
    unsigned short* __restrict__ Pf, float* __restrict__ R, int n) {
  __shared__ float hT[64][68];   // transposed h tile, padded
  __shared__ float W2[64][128];  // [k][j]: j<64 -> Wl, else Wr
  int t = threadIdx.x;
  int n0 = blockIdx.x * 64;

  for (int idx = t; idx < 64 * 128; idx += 256) {
    int k = idx >> 7, j = idx & 127;
    W2[k][j] = (j < 64) ? Wl[k * 64 + j] : Wr[k * 64 + (j - 64)];
  }
  for (int idx = t; idx < 64 * 16; idx += 256) {
    int r = idx >> 4;
    int k4 = (idx & 15) * 4;
    int nn = n0 + r;
    float4 hv = (nn < n) ? *(const float4*)&h[(size_t)nn * 64 + k4]
                         : make_float4(0.f, 0.f, 0.f, 0.f);
    hT[k4 + 0][r] = hv.x;
    hT[k4 + 1][r] = hv.y;
    hT[k4 + 2][r] = hv.z;
    hT[k4 + 3][r] = hv.w;
  }
  __syncthreads();

  int j0 = (t & 15) * 8;
  int r0 = (t >> 4) * 4;
  float acc[4][8] = {};
#pragma unroll 8
  for (int k = 0; k < 64; ++k) {
    float4 hv = *(const float4*)&hT[k][r0];
    float wv[8];
    *(float4*)&wv[0] = *(const float4*)&W2[k][j0];
    *(float4*)&wv[4] = *(const float4*)&W2[k][j0 + 4];
    float hr[4] = {hv.x, hv.y, hv.z, hv.w};
#pragma unroll
    for (int r = 0; r < 4; ++r)
#pragma unroll
      for (int c = 0; c < 8; ++c) acc[r][c] = fmaf(hr[r], wv[c], acc[r][c]);
  }

  if (j0 < 64) {
#pragma unroll
    for (int r = 0; r < 4; ++r) {
      int nn = n0 + r0 + r;
      if (nn < n) {
        union { _Float16 hh[8]; uint4 u4; } pk;
#pragma unroll
        for (int c = 0; c < 8; ++c) pk.hh[c] = (_Float16)acc[r][c];
        *(uint4*)&Pf[(size_t)nn * 64 + j0] = pk.u4;
      }
    }
  } else {
    int jj = j0 - 64;
    float4 b0 = *(const float4*)&bl[jj];
    float4 b1 = *(const float4*)&bl[jj + 4];
#pragma unroll
    for (int r = 0; r < 4; ++r) {
      int nn = n0 + r0 + r;
      if (nn < n) {
        *(float4*)&R[(size_t)nn * 64 + jj] =
            make_float4(acc[r][0] + b0.x, acc[r][1] + b0.y, acc[r][2] + b0.z, acc[r][3] + b0.w);
        *(float4*)&R[(size_t)nn * 64 + jj + 4] =
            make_float4(acc[r][4] + b1.x, acc[r][5] + b1.y, acc[r][6] + b1.z, acc[r][7] + b1.w);
      }
    }
  }
}

// ---- fused gather + activation. One wave per node. Lane l: q=l&15 covers
// dims 4q..4q+3 (uint2 = 4 f16), g=l>>4 covers edge sub-slot. Per 16-edge
// batch: 1 csr load, 4 shfl, 4 dwordx2 loads (4 rows/instr), 8 v_pk_add_f16,
// flush to f32. Cross-group reduce via shfl_xor(16,32); lanes 0-15 epilogue.
// MODE 0 relu; 1 relu+residual; 2 plain+L2-normalize.
template <int MODE>
__global__ __launch_bounds__(256) void k_gather(
    const uint2* __restrict__ P2, const float* __restrict__ R,
    const float* __restrict__ hres, const int* __restrict__ csr,
    const int* __restrict__ rs, const float* __restrict__ invdeg,
    float* __restrict__ hout, int n) {
  typedef _Float16 h2 __attribute__((ext_vector_type(2)));
  union HU { unsigned u32; h2 h; };
  int l = threadIdx.x & 63;
  int v = (blockIdx.x << 2) + (threadIdx.x >> 6);
  if (v >= n) return;
  int q = l & 15;
  int g = l >> 4;
  int beg = rs[v], end = rs[v + 1];
  float idg = invdeg[v];
  float4 rv = *(const float4*)&R[((size_t)v << 6) + (q << 2)];
  float4 hv = make_float4(0.f, 0.f, 0.f, 0.f);
  if (MODE == 1) hv = *(const float4*)&hres[((size_t)v << 6) + (q << 2)];

  float s0 = 0.f, s1 = 0.f, s2 = 0.f, s3 = 0.f;
  int i = beg;
  for (; i + 16 <= end; i += 16) {
    int myidx = csr[i + q];  // one 64B line, lanes 16-63 broadcast
    h2 a0 = (h2)0, a1 = (h2)0;
#pragma unroll
    for (int t = 0; t < 4; ++t) {
      int sel = __shfl(myidx, 4 * t + g, 64);
      uint2 u = P2[(unsigned)((sel << 4) + q)];
      HU b0, b1;
      b0.u32 = u.x;
      b1.u32 = u.y;
      a0 += b0.h;
      a1 += b1.h;
    }
    s0 += (float)a0[0];
    s1 += (float)a0[1];
    s2 += (float)a1[0];
    s3 += (float)a1[1];
  }
  int r = end - i;
  if (r > 0) {  // tail, r in [1,15]
    int myidx = csr[i + (q < r ? q : 0)];
    h2 a0 = (h2)0, a1 = (h2)0;
#pragma unroll
    for (int t = 0; t < 4; ++t) {
      if (4 * t >= r) break;  // wave-uniform
      int e = 4 * t + g;
      int sel = __shfl(myidx, e < r ? e : 0, 64);  // all lanes active here
      if (e < r) {
        uint2 u = P2[(unsigned)((sel << 4) + q)];
        HU b0, b1;
        b0.u32 = u.x;
        b1.u32 = u.y;
        a0 += b0.h;
        a1 += b1.h;
      }
    }
    s0 += (float)a0[0];
    s1 += (float)a0[1];
    s2 += (float)a1[0];
    s3 += (float)a1[1];
  }
  // reduce across the 4 edge-subgroups (lanes l, l^16, l^32, l^48)
  s0 += __shfl_xor(s0, 16, 64); s0 += __shfl_xor(s0, 32, 64);
  s1 += __shfl_xor(s1, 16, 64); s1 += __shfl_xor(s1, 32, 64);
  s2 += __shfl_xor(s2, 16, 64); s2 += __shfl_xor(s2, 32, 64);
  s3 += __shfl_xor(s3, 16, 64); s3 += __shfl_xor(s3, 32, 64);

  if (l < 16) {
    float4 o;
    o.x = s0 * idg + rv.x;
    o.y = s1 * idg + rv.y;
    o.z = s2 * idg + rv.z;
    o.w = s3 * idg + rv.w;
    if (MODE == 0) {
      o.x = fmaxf(o.x, 0.f); o.y = fmaxf(o.y, 0.f);
      o.z = fmaxf(o.z, 0.f); o.w = fmaxf(o.w, 0.f);
    } else if (MODE == 1) {
      o.x = fmaxf(o.x, 0.f) + hv.x; o.y = fmaxf(o.y, 0.f) + hv.y;
      o.z = fmaxf(o.z, 0.f) + hv.z; o.w = fmaxf(o.w, 0.f) + hv.w;
    } else {
      float sq = o.x * o.x + o.y * o.y + o.z * o.z + o.w * o.w;
#pragma unroll
      for (int m = 1; m < 16; m <<= 1) sq += __shfl_xor(sq, m, 64);
      float nrm = fmaxf(sqrtf(sq), 1e-12f);
      o.x /= nrm; o.y /= nrm; o.z /= nrm; o.w /= nrm;
    }
    *(float4*)&hout[((size_t)v << 6) + (q << 2)] = o;
  }
}

extern "C" void kernel_launch(void* const* d_in, const int* in_sizes, int n_in,
                              void* d_out, int out_size, void* d_ws, size_t ws_size,
                              hipStream_t stream) {
  const float* x = (const float*)d_in[0];
  const unsigned int* eraw = (const unsigned int*)d_in[1];
  const float* Wl[4] = {(const float*)d_in[2], (const float*)d_in[5],
                        (const float*)d_in[8], (const float*)d_in[11]};
  const float* blv[4] = {(const float*)d_in[3], (const float*)d_in[6],
                         (const float*)d_in[9], (const float*)d_in[12]};
  const float* Wr[4] = {(const float*)d_in[4], (const float*)d_in[7],
                        (const float*)d_in[10], (const float*)d_in[13]};
  const int N = in_sizes[0] / 64;
  const int E = in_sizes[1] / 2;
  const int span = (N + 255) / 256;  // nodes per bucket; must be <= 512
  float* out = (float*)d_out;

  char* w = (char*)d_ws;
  size_t off = 0;
  int* flag = (int*)(w + off);        off = al256(off + 4);
  int* bucketCount = (int*)(w + off); off = al256(off + 256 * 4);
  int* boff = (int*)(w + off);        off = al256(off + 257 * 4);
  int* cursorB = (int*)(w + off);     off = al256(off + 256 * 4);
  int* csr = (int*)(w + off);         off = al256(off + (size_t)E * 4);
  float* invdeg = (float*)(w + off);  off = al256(off + (size_t)N * 4);
  int* rs = (int*)(w + off);          off = al256(off + (size_t)(N + 1) * 4);
  uint2* bdata = (uint2*)(w + off);   off = al256(off + (size_t)E * 8);
  float* hA = (float*)(w + off);      off = al256(off + (size_t)N * 64 * 4);
  unsigned short* Pf = (unsigned short*)(w + off); off = al256(off + (size_t)N * 64 * 2);
  float* R = (float*)(w + off);       off = al256(off + (size_t)N * 64 * 4);

  hipMemsetAsync(flag, 0, 4, stream);
  hipMemsetAsync(bucketCount, 0, 256 * 4, stream);

  int eb = (E + EPB - 1) / EPB;
  k_detect<<<1, 256, 0, stream>>>(eraw, E, flag);
  k_bcount<<<eb, 256, 0, stream>>>(eraw, E, span, flag, bucketCount);
  k_bscan<<<1, 256, 0, stream>>>(bucketCount, boff, cursorB, rs, N, E);
  k_bscatter<<<eb, 256, 0, stream>>>(eraw, E, span, flag, cursorB, bdata);
  k_bbuild<<<256, 256, 0, stream>>>(bdata, boff, span, N, csr, rs, invdeg);

  int gb = (N + 63) / 64;
  int nb4 = (N + 3) / 4;
  const uint2* P2 = (const uint2*)Pf;
  // Layer 1: x -> hA (relu)
  k_gemm<<<gb, 256, 0, stream>>>(x, Wl[0], Wr[0], blv[0], Pf, R, N);
  k_gather<0><<<nb4, 256, 0, stream>>>(P2, R, nullptr, csr, rs, invdeg, hA, N);
  // Layer 2: hA -> out (relu + residual hA)
  k_gemm<<<gb, 256, 0, stream>>>(hA, Wl[1], Wr[1], blv[1], Pf, R, N);
  k_gather<1><<<nb4, 256, 0, stream>>>(P2, R, hA, csr, rs, invdeg, out, N);
  // Layer 3: out -> hA (relu + residual out)
  k_gemm<<<gb, 256, 0, stream>>>(out, Wl[2], Wr[2], blv[2], Pf, R, N);
  k_gather<1><<<nb4, 256, 0, stream>>>(P2, R, out, csr, rs, invdeg, hA, N);
  // Layer 4: hA -> out (no act, L2-normalize rows)
  k_gemm<<<gb, 256, 0, stream>>>(hA, Wl[3], Wr[3], blv[3], Pf, R, N);
  k_gather<2><<<nb4, 256, 0, stream>>>(P2, R, nullptr, csr, rs, invdeg, out, N);
}

// Round 8
// 328.415 us; speedup vs baseline: 3.1113x; 1.1770x over previous
//
#include <hip/hip_runtime.h>

// GraphSAGE 4-layer encoder, N=100000 nodes, d=64, E=1.6M edges.
//   1. CSR build via 2-level bucket sort (no per-node global atomics).
//   2. Per layer: MFMA GEMM (f16 in, f32 acc): P = h@Wl (f16), R = h@Wr + bl
//      (f32); fused gather: h_out = act(invdeg*sum P[nbr] + R) [+res] [L2n].
// R7->R8: GEMM moved from f32 VALU (~30us each) to mfma_f32_16x16x32_f16
// (h staged f16 in LDS, XOR-swizzled; W f16 in registers from L1).
// Gather: csr prefetch hoisted one batch ahead (break csr->shfl->load chain).

#include <hip/hip_bf16.h>

static inline size_t al256(size_t x) { return (x + 255) & ~(size_t)255; }

#define EPB 8192  // edges per block in bucket passes

typedef _Float16 f16x8 __attribute__((ext_vector_type(8)));
typedef float f32x4 __attribute__((ext_vector_type(4)));

// ---- edge dtype detection: int64 little-endian values < 2^31 have all odd
// 32-bit words zero. flag=1 -> int32, flag=0 -> int64.
__global__ void k_detect(const unsigned int* __restrict__ raw, int E, int* __restrict__ flag) {
  int nz = 0;
#pragma unroll
  for (int k = 0; k < 64; ++k) {
    int i = threadIdx.x + (k << 8);
    if (i < E && raw[2 * (size_t)i + 1] != 0u) nz = 1;
  }
  unsigned long long b = __ballot(nz != 0);
  if ((threadIdx.x & 63) == 0 && b) atomicOr(flag, 1);
}

// ---- pass A: bucket counts via LDS histogram.
__global__ __launch_bounds__(256) void k_bcount(const unsigned int* __restrict__ raw, int E,
                                                int span, const int* __restrict__ flag,
                                                int* __restrict__ bucketCount) {
  __shared__ int lh[256];
  int t = threadIdx.x;
  lh[t] = 0;
  __syncthreads();
  int f = *flag;
  int base = blockIdx.x * EPB;
#pragma unroll 4
  for (int k = 0; k < EPB / 256; ++k) {
    int i = base + k * 256 + t;
    if (i < E) {
      int dst = f ? (int)raw[E + i] : (int)raw[2 * (size_t)(E + i)];
      atomicAdd(&lh[dst / span], 1);
    }
  }
  __syncthreads();
  int c = lh[t];
  if (c) atomicAdd(&bucketCount[t], c);
}

// ---- scan 256 bucket counts -> boff[257], init cursorB, rs[N]=E.
__global__ void k_bscan(const int* __restrict__ bucketCount, int* __restrict__ boff,
                        int* __restrict__ cursorB, int* __restrict__ rs, int N, int E) {
  __shared__ int sa[256], sb[256];
  int t = threadIdx.x;
  int v = bucketCount[t];
  sa[t] = v;
  __syncthreads();
  int* s = sa;
  int* d = sb;
  for (int off = 1; off < 256; off <<= 1) {
    d[t] = s[t] + (t >= off ? s[t - off] : 0);
    __syncthreads();
    int* tmp = s; s = d; d = tmp;
  }
  int inc = s[t];
  int ex = inc - v;
  boff[t] = ex;
  cursorB[t] = ex;
  if (t == 255) boff[256] = inc;
  if (t == 0) rs[N] = E;
}

// ---- pass B: scatter (src,dst) pairs into bucket-contiguous bdata.
__global__ __launch_bounds__(256) void k_bscatter(const unsigned int* __restrict__ raw, int E,
                                                  int span, const int* __restrict__ flag,
                                                  int* __restrict__ cursorB,
                                                  uint2* __restrict__ bdata) {
  __shared__ int lh[256], lcur[256], gbase[256];
  int t = threadIdx.x;
  lh[t] = 0;
  lcur[t] = 0;
  __syncthreads();
  int f = *flag;
  int base = blockIdx.x * EPB;
#pragma unroll 4
  for (int k = 0; k < EPB / 256; ++k) {
    int i = base + k * 256 + t;
    if (i < E) {
      int dst = f ? (int)raw[E + i] : (int)raw[2 * (size_t)(E + i)];
      atomicAdd(&lh[dst / span], 1);
    }
  }
  __syncthreads();
  int c = lh[t];
  gbase[t] = c ? atomicAdd(&cursorB[t], c) : 0;
  __syncthreads();
#pragma unroll 4
  for (int k = 0; k < EPB / 256; ++k) {
    int i = base + k * 256 + t;
    if (i < E) {
      int s_, d_;
      if (f) { s_ = (int)raw[i]; d_ = (int)raw[E + i]; }
      else   { s_ = (int)raw[2 * (size_t)i]; d_ = (int)raw[2 * (size_t)(E + i)]; }
      int b = d_ / span;
      int pos = atomicAdd(&lcur[b], 1);
      bdata[(size_t)gbase[b] + pos] = make_uint2((unsigned)s_, (unsigned)d_);
    }
  }
}

// ---- pass C: one block per bucket. Node histogram + scan in LDS, write
// rs/invdeg, scatter src ids into the bucket's contiguous csr window.
// Requires span <= 512 (N <= 131072).
__global__ __launch_bounds__(256) void k_bbuild(const uint2* __restrict__ bdata,
                                                const int* __restrict__ boff, int span, int N,
                                                int* __restrict__ csr, int* __restrict__ rs,
                                                float* __restrict__ invdeg) {
  __shared__ int cnt[512], sa[512], sb[512], cur[512];
  int b = blockIdx.x;
  int t = threadIdx.x;
  int node0 = b * span;
  int beg = boff[b], end = boff[b + 1];
  cnt[t] = 0;
  cnt[t + 256] = 0;
  __syncthreads();
  for (int i = beg + t; i < end; i += 256) {
    int d = (int)bdata[i].y - node0;
    atomicAdd(&cnt[d], 1);
  }
  __syncthreads();
  sa[t] = cnt[t];
  sa[t + 256] = cnt[t + 256];
  __syncthreads();
  int* s = sa;
  int* d = sb;
  for (int off = 1; off < 512; off <<= 1) {
    d[t] = s[t] + (t >= off ? s[t - off] : 0);
    int i2 = t + 256;
    d[i2] = s[i2] + (i2 >= off ? s[i2 - off] : 0);
    __syncthreads();
    int* tmp = s; s = d; d = tmp;
  }
  int ex0 = s[t] - cnt[t];
  int ex1 = s[t + 256] - cnt[t + 256];
  cur[t] = ex0;
  cur[t + 256] = ex1;
  if (t < span) {
    int node = node0 + t;
    if (node < N) {
      rs[node] = beg + ex0;
      invdeg[node] = 1.0f / fmaxf((float)cnt[t], 1.0f);
    }
  }
  int t2 = t + 256;
  if (t2 < span) {
    int node = node0 + t2;
    if (node < N) {
      rs[node] = beg + ex1;
      invdeg[node] = 1.0f / fmaxf((float)cnt[t2], 1.0f);
    }
  }
  __syncthreads();
  for (int i = beg + t; i < end; i += 256) {
    uint2 p = bdata[i];
    int dd = (int)p.y - node0;
    int pos = atomicAdd(&cur[dd], 1);
    csr[beg + pos] = (int)p.x;
  }
}

// ---- MFMA GEMM: P(f16) = h @ Wl ; R(f32) = h @ Wr + bl.
// Block: 256 thr = 4 waves, tile 64 rows x 128 cols (waves 0-1 -> P cols,
// waves 2-3 -> R cols). A (h->f16) in LDS [row][k], byte^=(row&7)<<4 swizzle.
// B (W->f16) in registers: per wave 4 frags from L1-resident W.
// A/B frag: lane l holds 8 contiguous k at k=(l>>4)*8(+32*kk), row/col=l&15.
// C frag: col=lane&15, row=(lane>>4)*4+reg.
__global__ __launch_bounds__(256) void k_gemm(
    const float* __restrict__ h, const float* __restrict__ Wl,
    const float* __restrict__ Wr, const float* __restrict__ bl,
    unsigned short* __restrict__ Pf, float* __restrict__ R, int n) {
  __shared__ uint4 hAu[512];  // 8KB: 64 rows x 64 f16 (128B/row), swizzled
  char* hAraw = (char*)hAu;
  int t = threadIdx.x;
  int n0 = blockIdx.x * 64;
  int w = t >> 6;
  int l = t & 63;
  int lo16 = l & 15;
  int g = l >> 4;

  // stage A: 1024 float4 -> 4/thread; f32->f16, 8B LDS writes (swizzled)
#pragma unroll
  for (int c = 0; c < 4; ++c) {
    int idx = t + c * 256;
    int row = idx >> 4;
    int fc = idx & 15;
    int nn = n0 + row;
    float4 hv = (nn < n) ? *(const float4*)&h[(size_t)nn * 64 + fc * 4]
                         : make_float4(0.f, 0.f, 0.f, 0.f);
    union { _Float16 p[4]; uint2 u; } cv;
    cv.p[0] = (_Float16)hv.x; cv.p[1] = (_Float16)hv.y;
    cv.p[2] = (_Float16)hv.z; cv.p[3] = (_Float16)hv.w;
    int byte = (row * 128 + fc * 8) ^ ((row & 7) << 4);
    *(uint2*)(hAraw + byte) = cv.u;
  }

  // B frags to registers (wave-uniform W half)
  const float* Wsel = (w < 2) ? Wl : Wr;
  int colbase = (w & 1) * 32;
  f16x8 bfr[2][2];
#pragma unroll
  for (int nf = 0; nf < 2; ++nf) {
    int j = colbase + nf * 16 + lo16;
#pragma unroll
    for (int kk = 0; kk < 2; ++kk) {
      int k0 = kk * 32 + g * 8;
      f16x8 bb;
#pragma unroll
      for (int s = 0; s < 8; ++s) bb[s] = (_Float16)Wsel[(k0 + s) * 64 + j];
      bfr[nf][kk] = bb;
    }
  }
  __syncthreads();

  f32x4 acc[4][2];
#pragma unroll
  for (int mf = 0; mf < 4; ++mf)
#pragma unroll
    for (int nf = 0; nf < 2; ++nf) acc[mf][nf] = (f32x4){0.f, 0.f, 0.f, 0.f};

#pragma unroll
  for (int mf = 0; mf < 4; ++mf) {
    int row = mf * 16 + lo16;
    int swz = (row & 7) << 4;
    f16x8 av0 = *(const f16x8*)(hAraw + row * 128 + ((g * 16) ^ swz));
    f16x8 av1 = *(const f16x8*)(hAraw + row * 128 + ((64 + g * 16) ^ swz));
#pragma unroll
    for (int nf = 0; nf < 2; ++nf) {
      acc[mf][nf] = __builtin_amdgcn_mfma_f32_16x16x32_f16(av0, bfr[nf][0], acc[mf][nf], 0, 0, 0);
      acc[mf][nf] = __builtin_amdgcn_mfma_f32_16x16x32_f16(av1, bfr[nf][1], acc[mf][nf], 0, 0, 0);
    }
  }

  // epilogue: waves 0-1 -> P (f16), waves 2-3 -> R = acc + bl (f32)
#pragma unroll
  for (int nf = 0; nf < 2; ++nf) {
    int col = colbase + nf * 16 + lo16;  // 0..63 within half
    float bv = (w >= 2) ? bl[col] : 0.f;
#pragma unroll
    for (int mf = 0; mf < 4; ++mf) {
#pragma unroll
      for (int r = 0; r < 4; ++r) {
        int grow = n0 + mf * 16 + g * 4 + r;
        if (grow < n) {
          float v = acc[mf][nf][r];
          if (w < 2) {
            union { _Float16 hh; unsigned short us; } cv;
            cv.hh = (_Float16)v;
            Pf[(size_t)grow * 64 + col] = cv.us;
          } else {
            R[(size_t)grow * 64 + col] = v + bv;
          }
        }
      }
    }
  }
}

// ---- fused gather + activation. One wave per node. Lane l: q=l&15 covers
// dims 4q..4q+3 (uint2 = 4 f16), g=l>>4 covers edge sub-slot. Per 16-edge
// batch: 1 csr load (prefetched one batch ahead), 4 shfl, 4 dwordx2 loads,
// 8 v_pk_add_f16, flush to f32. Reduce via shfl_xor(16,32); lanes 0-15 store.
// MODE 0 relu; 1 relu+residual; 2 plain+L2-normalize.
template <int MODE>
__global__ __launch_bounds__(256) void k_gather(
    const uint2* __restrict__ P2, const float* __restrict__ R,
    const float* __restrict__ hres, const int* __restrict__ csr,
    const int* __restrict__ rs, const float* __restrict__ invdeg,
    float* __restrict__ hout, int n) {
  typedef _Float16 h2 __attribute__((ext_vector_type(2)));
  union HU { unsigned u32; h2 h; };
  int l = threadIdx.x & 63;
  int v = (blockIdx.x << 2) + (threadIdx.x >> 6);
  if (v >= n) return;
  int q = l & 15;
  int g = l >> 4;
  int beg = rs[v], end = rs[v + 1];
  float idg = invdeg[v];
  float4 rv = *(const float4*)&R[((size_t)v << 6) + (q << 2)];
  float4 hv = make_float4(0.f, 0.f, 0.f, 0.f);
  if (MODE == 1) hv = *(const float4*)&hres[((size_t)v << 6) + (q << 2)];

  float s0 = 0.f, s1 = 0.f, s2 = 0.f, s3 = 0.f;
  int i = beg;
  int rem = end - beg;
  int myidx = 0;
  if (rem > 0) myidx = csr[i + (q < rem ? q : (rem - 1))];
  for (; i + 16 <= end;) {
    int inext = i + 16;
    int remn = end - inext;
    int nxt = 0;
    if (remn > 0) nxt = csr[inext + (q < remn ? q : (remn - 1))];  // prefetch
    h2 a0 = (h2)0, a1 = (h2)0;
#pragma unroll
    for (int t = 0; t < 4; ++t) {
      int sel = __shfl(myidx, 4 * t + g, 64);
      uint2 u = P2[(unsigned)((sel << 4) + q)];
      HU b0, b1;
      b0.u32 = u.x;
      b1.u32 = u.y;
      a0 += b0.h;
      a1 += b1.h;
    }
    s0 += (float)a0[0];
    s1 += (float)a0[1];
    s2 += (float)a1[0];
    s3 += (float)a1[1];
    myidx = nxt;
    i = inext;
  }
  int r = end - i;
  if (r > 0) {  // tail, r in [1,15]; myidx already prefetched (clamped)
    h2 a0 = (h2)0, a1 = (h2)0;
#pragma unroll
    for (int t = 0; t < 4; ++t) {
      if (4 * t >= r) break;  // wave-uniform
      int e = 4 * t + g;
      int sel = __shfl(myidx, e < r ? e : 0, 64);
      if (e < r) {
        uint2 u = P2[(unsigned)((sel << 4) + q)];
        HU b0, b1;
        b0.u32 = u.x;
        b1.u32 = u.y;
        a0 += b0.h;
        a1 += b1.h;
      }
    }
    s0 += (float)a0[0];
    s1 += (float)a0[1];
    s2 += (float)a1[0];
    s3 += (float)a1[1];
  }
  s0 += __shfl_xor(s0, 16, 64); s0 += __shfl_xor(s0, 32, 64);
  s1 += __shfl_xor(s1, 16, 64); s1 += __shfl_xor(s1, 32, 64);
  s2 += __shfl_xor(s2, 16, 64); s2 += __shfl_xor(s2, 32, 64);
  s3 += __shfl_xor(s3, 16, 64); s3 += __shfl_xor(s3, 32, 64);

  if (l < 16) {
    float4 o;
    o.x = s0 * idg + rv.x;
    o.y = s1 * idg + rv.y;
    o.z = s2 * idg + rv.z;
    o.w = s3 * idg + rv.w;
    if (MODE == 0) {
      o.x = fmaxf(o.x, 0.f); o.y = fmaxf(o.y, 0.f);
      o.z = fmaxf(o.z, 0.f); o.w = fmaxf(o.w, 0.f);
    } else if (MODE == 1) {
      o.x = fmaxf(o.x, 0.f) + hv.x; o.y = fmaxf(o.y, 0.f) + hv.y;
      o.z = fmaxf(o.z, 0.f) + hv.z; o.w = fmaxf(o.w, 0.f) + hv.w;
    } else {
      float sq = o.x * o.x + o.y * o.y + o.z * o.z + o.w * o.w;
#pragma unroll
      for (int m = 1; m < 16; m <<= 1) sq += __shfl_xor(sq, m, 64);
      float nrm = fmaxf(sqrtf(sq), 1e-12f);
      o.x /= nrm; o.y /= nrm; o.z /= nrm; o.w /= nrm;
    }
    *(float4*)&hout[((size_t)v << 6) + (q << 2)] = o;
  }
}

extern "C" void kernel_launch(void* const* d_in, const int* in_sizes, int n_in,
                              void* d_out, int out_size, void* d_ws, size_t ws_size,
                              hipStream_t stream) {
  const float* x = (const float*)d_in[0];
  const unsigned int* eraw = (const unsigned int*)d_in[1];
  const float* Wl[4] = {(const float*)d_in[2], (const float*)d_in[5],
                        (const float*)d_in[8], (const float*)d_in[11]};
  const float* blv[4] = {(const float*)d_in[3], (const float*)d_in[6],
                         (const float*)d_in[9], (const float*)d_in[12]};
  const float* Wr[4] = {(const float*)d_in[4], (const float*)d_in[7],
                        (const float*)d_in[10], (const float*)d_in[13]};
  const int N = in_sizes[0] / 64;
  const int E = in_sizes[1] / 2;
  const int span = (N + 255) / 256;  // nodes per bucket; must be <= 512
  float* out = (float*)d_out;

  char* w = (char*)d_ws;
  size_t off = 0;
  int* flag = (int*)(w + off);        off = al256(off + 4);
  int* bucketCount = (int*)(w + off); off = al256(off + 256 * 4);
  int* boff = (int*)(w + off);        off = al256(off + 257 * 4);
  int* cursorB = (int*)(w + off);     off = al256(off + 256 * 4);
  int* csr = (int*)(w + off);         off = al256(off + (size_t)E * 4);
  float* invdeg = (float*)(w + off);  off = al256(off + (size_t)N * 4);
  int* rs = (int*)(w + off);          off = al256(off + (size_t)(N + 1) * 4);
  uint2* bdata = (uint2*)(w + off);   off = al256(off + (size_t)E * 8);
  float* hA = (float*)(w + off);      off = al256(off + (size_t)N * 64 * 4);
  unsigned short* Pf = (unsigned short*)(w + off); off = al256(off + (size_t)N * 64 * 2);
  float* R = (float*)(w + off);       off = al256(off + (size_t)N * 64 * 4);

  hipMemsetAsync(flag, 0, 4, stream);
  hipMemsetAsync(bucketCount, 0, 256 * 4, stream);

  int eb = (E + EPB - 1) / EPB;
  k_detect<<<1, 256, 0, stream>>>(eraw, E, flag);
  k_bcount<<<eb, 256, 0, stream>>>(eraw, E, span, flag, bucketCount);
  k_bscan<<<1, 256, 0, stream>>>(bucketCount, boff, cursorB, rs, N, E);
  k_bscatter<<<eb, 256, 0, stream>>>(eraw, E, span, flag, cursorB, bdata);
  k_bbuild<<<256, 256, 0, stream>>>(bdata, boff, span, N, csr, rs, invdeg);

  int gb = (N + 63) / 64;
  int nb4 = (N + 3) / 4;
  const uint2* P2 = (const uint2*)Pf;
  // Layer 1: x -> hA (relu)
  k_gemm<<<gb, 256, 0, stream>>>(x, Wl[0], Wr[0], blv[0], Pf, R, N);
  k_gather<0><<<nb4, 256, 0, stream>>>(P2, R, nullptr, csr, rs, invdeg, hA, N);
  // Layer 2: hA -> out (relu + residual hA)
  k_gemm<<<gb, 256, 0, stream>>>(hA, Wl[1], Wr[1], blv[1], Pf, R, N);
  k_gather<1><<<nb4, 256, 0, stream>>>(P2, R, hA, csr, rs, invdeg, out, N);
  // Layer 3: out -> hA (relu + residual out)
  k_gemm<<<gb, 256, 0, stream>>>(out, Wl[2], Wr[2], blv[2], Pf, R, N);
  k_gather<1><<<nb4, 256, 0, stream>>>(P2, R, out, csr, rs, invdeg, hA, N);
  // Layer 4: hA -> out (no act, L2-normalize rows)
  k_gemm<<<gb, 256, 0, stream>>>(hA, Wl[3], Wr[3], blv[3], Pf, R, N);
  k_gather<2><<<nb4, 256, 0, stream>>>(P2, R, nullptr, csr, rs, invdeg, out, N);
}

// Round 9
// 318.086 us; speedup vs baseline: 3.2123x; 1.0325x over previous
//
#include <hip/hip_runtime.h>

// GraphSAGE 4-layer encoder, N=100000 nodes, d=64, E=1.6M edges.
//   1. CSR build via 2-level bucket sort (no per-node global atomics),
//      bdata packed uint32 (src 17b | dstoff 9b; requires N <= 131072).
//   2. Per layer: MFMA GEMM (f16 in, f32 acc): P = h@Wl (f16), R = h@Wr + bl
//      (f16); fused gather: h_out = act(invdeg*sum P[nbr] + R) [+res] [L2n].
// R8->R9: all sequential per-node state (h intermediates, R) stored f16 --
// GEMM already cast h->f16 for MFMA, so h-f16 storage adds no GEMM-path
// error. GEMM read + gather R/res/out traffic halved.

#include <hip/hip_bf16.h>

static inline size_t al256(size_t x) { return (x + 255) & ~(size_t)255; }

#define EPB 8192  // edges per block in bucket passes

typedef _Float16 f16x8 __attribute__((ext_vector_type(8)));
typedef float f32x4 __attribute__((ext_vector_type(4)));

// ---- edge dtype detection: int64 little-endian values < 2^31 have all odd
// 32-bit words zero. flag=1 -> int32, flag=0 -> int64.
__global__ void k_detect(const unsigned int* __restrict__ raw, int E, int* __restrict__ flag) {
  int nz = 0;
#pragma unroll
  for (int k = 0; k < 64; ++k) {
    int i = threadIdx.x + (k << 8);
    if (i < E && raw[2 * (size_t)i + 1] != 0u) nz = 1;
  }
  unsigned long long b = __ballot(nz != 0);
  if ((threadIdx.x & 63) == 0 && b) atomicOr(flag, 1);
}

// ---- pass A: bucket counts via LDS histogram.
__global__ __launch_bounds__(256) void k_bcount(const unsigned int* __restrict__ raw, int E,
                                                int span, const int* __restrict__ flag,
                                                int* __restrict__ bucketCount) {
  __shared__ int lh[256];
  int t = threadIdx.x;
  lh[t] = 0;
  __syncthreads();
  int f = *flag;
  int base = blockIdx.x * EPB;
#pragma unroll 4
  for (int k = 0; k < EPB / 256; ++k) {
    int i = base + k * 256 + t;
    if (i < E) {
      int dst = f ? (int)raw[E + i] : (int)raw[2 * (size_t)(E + i)];
      atomicAdd(&lh[dst / span], 1);
    }
  }
  __syncthreads();
  int c = lh[t];
  if (c) atomicAdd(&bucketCount[t], c);
}

// ---- scan 256 bucket counts -> boff[257], init cursorB, rs[N]=E.
__global__ void k_bscan(const int* __restrict__ bucketCount, int* __restrict__ boff,
                        int* __restrict__ cursorB, int* __restrict__ rs, int N, int E) {
  __shared__ int sa[256], sb[256];
  int t = threadIdx.x;
  int v = bucketCount[t];
  sa[t] = v;
  __syncthreads();
  int* s = sa;
  int* d = sb;
  for (int off = 1; off < 256; off <<= 1) {
    d[t] = s[t] + (t >= off ? s[t - off] : 0);
    __syncthreads();
    int* tmp = s; s = d; d = tmp;
  }
  int inc = s[t];
  int ex = inc - v;
  boff[t] = ex;
  cursorB[t] = ex;
  if (t == 255) boff[256] = inc;
  if (t == 0) rs[N] = E;
}

// ---- pass B: scatter packed (dstoff<<17 | src) into bucket-contiguous bdata.
__global__ __launch_bounds__(256) void k_bscatter(const unsigned int* __restrict__ raw, int E,
                                                  int span, const int* __restrict__ flag,
                                                  int* __restrict__ cursorB,
                                                  unsigned* __restrict__ bdata) {
  __shared__ int lh[256], lcur[256], gbase[256];
  int t = threadIdx.x;
  lh[t] = 0;
  lcur[t] = 0;
  __syncthreads();
  int f = *flag;
  int base = blockIdx.x * EPB;
#pragma unroll 4
  for (int k = 0; k < EPB / 256; ++k) {
    int i = base + k * 256 + t;
    if (i < E) {
      int dst = f ? (int)raw[E + i] : (int)raw[2 * (size_t)(E + i)];
      atomicAdd(&lh[dst / span], 1);
    }
  }
  __syncthreads();
  int c = lh[t];
  gbase[t] = c ? atomicAdd(&cursorB[t], c) : 0;
  __syncthreads();
#pragma unroll 4
  for (int k = 0; k < EPB / 256; ++k) {
    int i = base + k * 256 + t;
    if (i < E) {
      int s_, d_;
      if (f) { s_ = (int)raw[i]; d_ = (int)raw[E + i]; }
      else   { s_ = (int)raw[2 * (size_t)i]; d_ = (int)raw[2 * (size_t)(E + i)]; }
      int b = d_ / span;
      int pos = atomicAdd(&lcur[b], 1);
      bdata[(size_t)gbase[b] + pos] = ((unsigned)(d_ - b * span) << 17) | (unsigned)s_;
    }
  }
}

// ---- pass C: one block per bucket. Node histogram + scan in LDS, write
// rs/invdeg, scatter src ids into the bucket's contiguous csr window.
// Requires span <= 512 (N <= 131072).
__global__ __launch_bounds__(256) void k_bbuild(const unsigned* __restrict__ bdata,
                                                const int* __restrict__ boff, int span, int N,
                                                int* __restrict__ csr, int* __restrict__ rs,
                                                float* __restrict__ invdeg) {
  __shared__ int cnt[512], sa[512], sb[512], cur[512];
  int b = blockIdx.x;
  int t = threadIdx.x;
  int node0 = b * span;
  int beg = boff[b], end = boff[b + 1];
  cnt[t] = 0;
  cnt[t + 256] = 0;
  __syncthreads();
  for (int i = beg + t; i < end; i += 256) {
    atomicAdd(&cnt[bdata[i] >> 17], 1);
  }
  __syncthreads();
  sa[t] = cnt[t];
  sa[t + 256] = cnt[t + 256];
  __syncthreads();
  int* s = sa;
  int* d = sb;
  for (int off = 1; off < 512; off <<= 1) {
    d[t] = s[t] + (t >= off ? s[t - off] : 0);
    int i2 = t + 256;
    d[i2] = s[i2] + (i2 >= off ? s[i2 - off] : 0);
    __syncthreads();
    int* tmp = s; s = d; d = tmp;
  }
  int ex0 = s[t] - cnt[t];
  int ex1 = s[t + 256] - cnt[t + 256];
  cur[t] = ex0;
  cur[t + 256] = ex1;
  if (t < span) {
    int node = node0 + t;
    if (node < N) {
      rs[node] = beg + ex0;
      invdeg[node] = 1.0f / fmaxf((float)cnt[t], 1.0f);
    }
  }
  int t2 = t + 256;
  if (t2 < span) {
    int node = node0 + t2;
    if (node < N) {
      rs[node] = beg + ex1;
      invdeg[node] = 1.0f / fmaxf((float)cnt[t2], 1.0f);
    }
  }
  __syncthreads();
  for (int i = beg + t; i < end; i += 256) {
    unsigned p = bdata[i];
    int pos = atomicAdd(&cur[p >> 17], 1);
    csr[beg + pos] = (int)(p & 0x1FFFFu);
  }
}

// ---- MFMA GEMM: P(f16) = h @ Wl ; R(f16) = h @ Wr + bl.
// Block: 256 thr = 4 waves, tile 64 rows x 128 cols (waves 0-1 -> P cols,
// waves 2-3 -> R cols). A in LDS [row][k] f16, byte^=(row&7)<<4 swizzle.
// IT=0: h is f32 (cast while staging); IT=1: h is f16 (straight copy).
// A/B frag: lane l holds 8 contiguous k at k=(l>>4)*8(+32*kk), row/col=l&15.
// C frag: col=lane&15, row=(lane>>4)*4+reg.
template <int IT>
__global__ __launch_bounds__(256) void k_gemm(
    const void* __restrict__ hv_, const float* __restrict__ Wl,
    const float* __restrict__ Wr, const float* __restrict__ bl,
    unsigned short* __restrict__ Pf, unsigned short* __restrict__ R16, int n) {
  __shared__ uint4 hAu[512];  // 8KB: 64 rows x 64 f16 (128B/row), swizzled
  char* hAraw = (char*)hAu;
  int t = threadIdx.x;
  int n0 = blockIdx.x * 64;
  int w = t >> 6;
  int l = t & 63;
  int lo16 = l & 15;
  int g = l >> 4;

  // stage A: 64 rows x 16 chunks of 8B; swizzled LDS writes
#pragma unroll
  for (int c = 0; c < 4; ++c) {
    int idx = t + c * 256;
    int row = idx >> 4;
    int fc = idx & 15;
    int nn = n0 + row;
    uint2 u = make_uint2(0u, 0u);
    if (nn < n) {
      if (IT == 0) {
        const float* h = (const float*)hv_;
        float4 hv = *(const float4*)&h[(size_t)nn * 64 + fc * 4];
        union { _Float16 p[4]; uint2 u; } cv;
        cv.p[0] = (_Float16)hv.x; cv.p[1] = (_Float16)hv.y;
        cv.p[2] = (_Float16)hv.z; cv.p[3] = (_Float16)hv.w;
        u = cv.u;
      } else {
        u = *(const uint2*)((const char*)hv_ + (size_t)nn * 128 + fc * 8);
      }
    }
    int byte = (row * 128 + fc * 8) ^ ((row & 7) << 4);
    *(uint2*)(hAraw + byte) = u;
  }

  // B frags to registers (wave-uniform W half)
  const float* Wsel = (w < 2) ? Wl : Wr;
  int colbase = (w & 1) * 32;
  f16x8 bfr[2][2];
#pragma unroll
  for (int nf = 0; nf < 2; ++nf) {
    int j = colbase + nf * 16 + lo16;
#pragma unroll
    for (int kk = 0; kk < 2; ++kk) {
      int k0 = kk * 32 + g * 8;
      f16x8 bb;
#pragma unroll
      for (int s = 0; s < 8; ++s) bb[s] = (_Float16)Wsel[(k0 + s) * 64 + j];
      bfr[nf][kk] = bb;
    }
  }
  __syncthreads();

  f32x4 acc[4][2];
#pragma unroll
  for (int mf = 0; mf < 4; ++mf)
#pragma unroll
    for (int nf = 0; nf < 2; ++nf) acc[mf][nf] = (f32x4){0.f, 0.f, 0.f, 0.f};

#pragma unroll
  for (int mf = 0; mf < 4; ++mf) {
    int row = mf * 16 + lo16;
    int swz = (row & 7) << 4;
    f16x8 av0 = *(const f16x8*)(hAraw + row * 128 + ((g * 16) ^ swz));
    f16x8 av1 = *(const f16x8*)(hAraw + row * 128 + ((64 + g * 16) ^ swz));
#pragma unroll
    for (int nf = 0; nf < 2; ++nf) {
      acc[mf][nf] = __builtin_amdgcn_mfma_f32_16x16x32_f16(av0, bfr[nf][0], acc[mf][nf], 0, 0, 0);
      acc[mf][nf] = __builtin_amdgcn_mfma_f32_16x16x32_f16(av1, bfr[nf][1], acc[mf][nf], 0, 0, 0);
    }
  }

  // epilogue: waves 0-1 -> P (f16), waves 2-3 -> R16 = f16(acc + bl)
#pragma unroll
  for (int nf = 0; nf < 2; ++nf) {
    int col = colbase + nf * 16 + lo16;  // 0..63 within half
    float bv = (w >= 2) ? bl[col] : 0.f;
#pragma unroll
    for (int mf = 0; mf < 4; ++mf) {
#pragma unroll
      for (int r = 0; r < 4; ++r) {
        int grow = n0 + mf * 16 + g * 4 + r;
        if (grow < n) {
          float v = acc[mf][nf][r];
          union { _Float16 hh; unsigned short us; } cv;
          if (w < 2) {
            cv.hh = (_Float16)v;
            Pf[(size_t)grow * 64 + col] = cv.us;
          } else {
            cv.hh = (_Float16)(v + bv);
            R16[(size_t)grow * 64 + col] = cv.us;
          }
        }
      }
    }
  }
}

// ---- fused gather + activation. One wave per node. Lane l: q=l&15 covers
// dims 4q..4q+3 (uint2 = 4 f16), g=l>>4 covers edge sub-slot. Per 16-edge
// batch: 1 csr load (prefetched one batch ahead), 4 shfl, 4 dwordx2 loads,
// 8 v_pk_add_f16, flush to f32. Reduce via shfl_xor(16,32); lanes 0-15 store.
// R/hres are f16. MODE 0 relu -> f16 out; 1 relu+residual -> f16 out;
// 2 plain+L2-normalize -> f32 out.
template <int MODE>
__global__ __launch_bounds__(256) void k_gather(
    const uint2* __restrict__ P2, const unsigned short* __restrict__ R16,
    const unsigned short* __restrict__ hres, const int* __restrict__ csr,
    const int* __restrict__ rs, const float* __restrict__ invdeg,
    void* __restrict__ hout, int n) {
  typedef _Float16 h2 __attribute__((ext_vector_type(2)));
  union HU { unsigned u32; h2 h; };
  union Q4 { uint2 u; _Float16 hh[4]; };
  int l = threadIdx.x & 63;
  int v = (blockIdx.x << 2) + (threadIdx.x >> 6);
  if (v >= n) return;
  int q = l & 15;
  int g = l >> 4;
  int beg = rs[v], end = rs[v + 1];
  float idg = invdeg[v];
  Q4 rq;
  rq.u = *(const uint2*)((const char*)R16 + (size_t)v * 128 + q * 8);
  Q4 hq;
  hq.u = make_uint2(0u, 0u);
  if (MODE == 1) hq.u = *(const uint2*)((const char*)hres + (size_t)v * 128 + q * 8);

  float s0 = 0.f, s1 = 0.f, s2 = 0.f, s3 = 0.f;
  int i = beg;
  int rem = end - beg;
  int myidx = 0;
  if (rem > 0) myidx = csr[i + (q < rem ? q : (rem - 1))];
  for (; i + 16 <= end;) {
    int inext = i + 16;
    int remn = end - inext;
    int nxt = 0;
    if (remn > 0) nxt = csr[inext + (q < remn ? q : (remn - 1))];  // prefetch
    h2 a0 = (h2)0, a1 = (h2)0;
#pragma unroll
    for (int t = 0; t < 4; ++t) {
      int sel = __shfl(myidx, 4 * t + g, 64);
      uint2 u = P2[(unsigned)((sel << 4) + q)];
      HU b0, b1;
      b0.u32 = u.x;
      b1.u32 = u.y;
      a0 += b0.h;
      a1 += b1.h;
    }
    s0 += (float)a0[0];
    s1 += (float)a0[1];
    s2 += (float)a1[0];
    s3 += (float)a1[1];
    myidx = nxt;
    i = inext;
  }
  int r = end - i;
  if (r > 0) {  // tail, r in [1,15]; myidx already prefetched (clamped)
    h2 a0 = (h2)0, a1 = (h2)0;
#pragma unroll
    for (int t = 0; t < 4; ++t) {
      if (4 * t >= r) break;  // wave-uniform
      int e = 4 * t + g;
      int sel = __shfl(myidx, e < r ? e : 0, 64);
      if (e < r) {
        uint2 u = P2[(unsigned)((sel << 4) + q)];
        HU b0, b1;
        b0.u32 = u.x;
        b1.u32 = u.y;
        a0 += b0.h;
        a1 += b1.h;
      }
    }
    s0 += (float)a0[0];
    s1 += (float)a0[1];
    s2 += (float)a1[0];
    s3 += (float)a1[1];
  }
  s0 += __shfl_xor(s0, 16, 64); s0 += __shfl_xor(s0, 32, 64);
  s1 += __shfl_xor(s1, 16, 64); s1 += __shfl_xor(s1, 32, 64);
  s2 += __shfl_xor(s2, 16, 64); s2 += __shfl_xor(s2, 32, 64);
  s3 += __shfl_xor(s3, 16, 64); s3 += __shfl_xor(s3, 32, 64);

  if (l < 16) {
    float4 o;
    o.x = s0 * idg + (float)rq.hh[0];
    o.y = s1 * idg + (float)rq.hh[1];
    o.z = s2 * idg + (float)rq.hh[2];
    o.w = s3 * idg + (float)rq.hh[3];
    if (MODE == 0) {
      o.x = fmaxf(o.x, 0.f); o.y = fmaxf(o.y, 0.f);
      o.z = fmaxf(o.z, 0.f); o.w = fmaxf(o.w, 0.f);
    } else if (MODE == 1) {
      o.x = fmaxf(o.x, 0.f) + (float)hq.hh[0];
      o.y = fmaxf(o.y, 0.f) + (float)hq.hh[1];
      o.z = fmaxf(o.z, 0.f) + (float)hq.hh[2];
      o.w = fmaxf(o.w, 0.f) + (float)hq.hh[3];
    } else {
      float sq = o.x * o.x + o.y * o.y + o.z * o.z + o.w * o.w;
#pragma unroll
      for (int m = 1; m < 16; m <<= 1) sq += __shfl_xor(sq, m, 64);
      float nrm = fmaxf(sqrtf(sq), 1e-12f);
      o.x /= nrm; o.y /= nrm; o.z /= nrm; o.w /= nrm;
    }
    if (MODE == 2) {
      *(float4*)&((float*)hout)[((size_t)v << 6) + (q << 2)] = o;
    } else {
      Q4 oq;
      oq.hh[0] = (_Float16)o.x; oq.hh[1] = (_Float16)o.y;
      oq.hh[2] = (_Float16)o.z; oq.hh[3] = (_Float16)o.w;
      *(uint2*)((char*)hout + (size_t)v * 128 + q * 8) = oq.u;
    }
  }
}

extern "C" void kernel_launch(void* const* d_in, const int* in_sizes, int n_in,
                              void* d_out, int out_size, void* d_ws, size_t ws_size,
                              hipStream_t stream) {
  const float* x = (const float*)d_in[0];
  const unsigned int* eraw = (const unsigned int*)d_in[1];
  const float* Wl[4] = {(const float*)d_in[2], (const float*)d_in[5],
                        (const float*)d_in[8], (const float*)d_in[11]};
  const float* blv[4] = {(const float*)d_in[3], (const float*)d_in[6],
                         (const float*)d_in[9], (const float*)d_in[12]};
  const float* Wr[4] = {(const float*)d_in[4], (const float*)d_in[7],
                        (const float*)d_in[10], (const float*)d_in[13]};
  const int N = in_sizes[0] / 64;
  const int E = in_sizes[1] / 2;
  const int span = (N + 255) / 256;  // nodes per bucket; must be <= 512
  float* out = (float*)d_out;

  char* w = (char*)d_ws;
  size_t off = 0;
  int* flag = (int*)(w + off);        off = al256(off + 4);
  int* bucketCount = (int*)(w + off); off = al256(off + 256 * 4);
  int* boff = (int*)(w + off);        off = al256(off + 257 * 4);
  int* cursorB = (int*)(w + off);     off = al256(off + 256 * 4);
  int* csr = (int*)(w + off);         off = al256(off + (size_t)E * 4);
  float* invdeg = (float*)(w + off);  off = al256(off + (size_t)N * 4);
  int* rs = (int*)(w + off);          off = al256(off + (size_t)(N + 1) * 4);
  unsigned* bdata = (unsigned*)(w + off); off = al256(off + (size_t)E * 4);
  unsigned short* hA = (unsigned short*)(w + off); off = al256(off + (size_t)N * 64 * 2);
  unsigned short* hB = (unsigned short*)(w + off); off = al256(off + (size_t)N * 64 * 2);
  unsigned short* Pf = (unsigned short*)(w + off); off = al256(off + (size_t)N * 64 * 2);
  unsigned short* R16 = (unsigned short*)(w + off); off = al256(off + (size_t)N * 64 * 2);

  hipMemsetAsync(flag, 0, 4, stream);
  hipMemsetAsync(bucketCount, 0, 256 * 4, stream);

  int eb = (E + EPB - 1) / EPB;
  k_detect<<<1, 256, 0, stream>>>(eraw, E, flag);
  k_bcount<<<eb, 256, 0, stream>>>(eraw, E, span, flag, bucketCount);
  k_bscan<<<1, 256, 0, stream>>>(bucketCount, boff, cursorB, rs, N, E);
  k_bscatter<<<eb, 256, 0, stream>>>(eraw, E, span, flag, cursorB, bdata);
  k_bbuild<<<256, 256, 0, stream>>>(bdata, boff, span, N, csr, rs, invdeg);

  int gb = (N + 63) / 64;
  int nb4 = (N + 3) / 4;
  const uint2* P2 = (const uint2*)Pf;
  // Layer 1: x(f32) -> hA (relu, f16)
  k_gemm<0><<<gb, 256, 0, stream>>>(x, Wl[0], Wr[0], blv[0], Pf, R16, N);
  k_gather<0><<<nb4, 256, 0, stream>>>(P2, R16, nullptr, csr, rs, invdeg, hA, N);
  // Layer 2: hA -> hB (relu + residual hA, f16)
  k_gemm<1><<<gb, 256, 0, stream>>>(hA, Wl[1], Wr[1], blv[1], Pf, R16, N);
  k_gather<1><<<nb4, 256, 0, stream>>>(P2, R16, hA, csr, rs, invdeg, hB, N);
  // Layer 3: hB -> hA (relu + residual hB, f16)
  k_gemm<1><<<gb, 256, 0, stream>>>(hB, Wl[2], Wr[2], blv[2], Pf, R16, N);
  k_gather<1><<<nb4, 256, 0, stream>>>(P2, R16, hB, csr, rs, invdeg, hA, N);
  // Layer 4: hA -> out (no act, L2-normalize rows, f32)
  k_gemm<1><<<gb, 256, 0, stream>>>(hA, Wl[3], Wr[3], blv[3], Pf, R16, N);
  k_gather<2><<<nb4, 256, 0, stream>>>(P2, R16, nullptr, csr, rs, invdeg, out, N);
}